// Round 6
// baseline (497.460 us; speedup 1.0000x reference)
//
#include <hip/hip_runtime.h>
#include <cstdint>
#include <cstddef>

#define NEG_SLOPE 0.01f

// ============================================================================
// GEMM kernels — register-blocked 4x4 micro-tiles, b128 LDS reads
// ============================================================================

__global__ __launch_bounds__(128) void gemm1_kernel(
    const float* __restrict__ h, const float* __restrict__ W,
    const float* __restrict__ a, float* __restrict__ z,
    float* __restrict__ s_src, float* __restrict__ s_dst, int N)
{
    __shared__ float Hl[64 * 140];
    __shared__ float Wl[128 * 32];
    int tid = threadIdx.x;
    int rowBase = blockIdx.x * 64;

    {
        const float4* W4 = (const float4*)W;
        float4* Wl4 = (float4*)Wl;
        for (int i = tid; i < 1024; i += 128) Wl4[i] = W4[i];
    }
    {
        const float4* h4 = (const float4*)h;
        for (int i = tid; i < 64 * 32; i += 128) {
            int r = i >> 5, kq = i & 31;
            float4 v = (rowBase + r < N) ? h4[(size_t)(rowBase + r) * 32 + kq]
                                         : make_float4(0.f, 0.f, 0.f, 0.f);
            *(float4*)&Hl[r * 140 + kq * 4] = v;
        }
    }
    __syncthreads();

    int wv   = tid >> 6;
    int lane = tid & 63;
    int g    = lane >> 3;
    int l8   = lane & 7;
    int r0   = wv * 32 + g * 4;
    int col4 = l8 * 4;

    float acc[4][4];
#pragma unroll
    for (int i = 0; i < 4; i++)
#pragma unroll
        for (int c = 0; c < 4; c++) acc[i][c] = 0.f;

    const float4* H4  = (const float4*)Hl;
    const float4* Wl4 = (const float4*)Wl;

#pragma unroll 2
    for (int kq = 0; kq < 32; kq++) {
        float4 w0 = Wl4[(kq * 4 + 0) * 8 + l8];
        float4 w1 = Wl4[(kq * 4 + 1) * 8 + l8];
        float4 w2 = Wl4[(kq * 4 + 2) * 8 + l8];
        float4 w3 = Wl4[(kq * 4 + 3) * 8 + l8];
#pragma unroll
        for (int i = 0; i < 4; i++) {
            float4 hv = H4[(r0 + i) * 35 + kq];
            acc[i][0] += hv.x * w0.x; acc[i][1] += hv.x * w0.y;
            acc[i][2] += hv.x * w0.z; acc[i][3] += hv.x * w0.w;
            acc[i][0] += hv.y * w1.x; acc[i][1] += hv.y * w1.y;
            acc[i][2] += hv.y * w1.z; acc[i][3] += hv.y * w1.w;
            acc[i][0] += hv.z * w2.x; acc[i][1] += hv.z * w2.y;
            acc[i][2] += hv.z * w2.z; acc[i][3] += hv.z * w2.w;
            acc[i][0] += hv.w * w3.x; acc[i][1] += hv.w * w3.y;
            acc[i][2] += hv.w * w3.z; acc[i][3] += hv.w * w3.w;
        }
    }

    float4 alo = ((const float4*)a)[l8];
    float4 ahi = ((const float4*)a)[8 + l8];
#pragma unroll
    for (int i = 0; i < 4; i++) {
        int row = rowBase + r0 + i;
        if (row < N) {
            float4 zv = make_float4(acc[i][0], acc[i][1], acc[i][2], acc[i][3]);
            *(float4*)&z[(size_t)row * 32 + col4] = zv;
            float ps = zv.x * alo.x + zv.y * alo.y + zv.z * alo.z + zv.w * alo.w;
            float pd = zv.x * ahi.x + zv.y * ahi.y + zv.z * ahi.z + zv.w * ahi.w;
            ps += __shfl_xor(ps, 1, 64); ps += __shfl_xor(ps, 2, 64); ps += __shfl_xor(ps, 4, 64);
            pd += __shfl_xor(pd, 1, 64); pd += __shfl_xor(pd, 2, 64); pd += __shfl_xor(pd, 4, 64);
            if (l8 == 0) { s_src[row] = ps; s_dst[row] = pd; }
        }
    }
}

__global__ __launch_bounds__(128) void gemm2_kernel(
    const float* __restrict__ h, const float* __restrict__ W,
    const float* __restrict__ a, float* __restrict__ z,
    float* __restrict__ s_src, float* __restrict__ s_dst, int N)
{
    __shared__ float Hl[64 * 44];
    __shared__ float Wl[32 * 32];
    int tid = threadIdx.x;
    int rowBase = blockIdx.x * 64;

    {
        const float4* W4 = (const float4*)W;
        float4* Wl4 = (float4*)Wl;
        for (int i = tid; i < 256; i += 128) Wl4[i] = W4[i];
    }
    {
        const float4* h4 = (const float4*)h;
        for (int i = tid; i < 64 * 8; i += 128) {
            int r = i >> 3, kq = i & 7;
            float4 v = (rowBase + r < N) ? h4[(size_t)(rowBase + r) * 8 + kq]
                                         : make_float4(0.f, 0.f, 0.f, 0.f);
            *(float4*)&Hl[r * 44 + kq * 4] = v;
        }
    }
    __syncthreads();

    int wv   = tid >> 6;
    int lane = tid & 63;
    int g    = lane >> 3;
    int l8   = lane & 7;
    int r0   = wv * 32 + g * 4;
    int col4 = l8 * 4;

    float acc[4][4];
#pragma unroll
    for (int i = 0; i < 4; i++)
#pragma unroll
        for (int c = 0; c < 4; c++) acc[i][c] = 0.f;

    const float4* H4  = (const float4*)Hl;
    const float4* Wl4 = (const float4*)Wl;

#pragma unroll
    for (int kq = 0; kq < 8; kq++) {
        float4 w0 = Wl4[(kq * 4 + 0) * 8 + l8];
        float4 w1 = Wl4[(kq * 4 + 1) * 8 + l8];
        float4 w2 = Wl4[(kq * 4 + 2) * 8 + l8];
        float4 w3 = Wl4[(kq * 4 + 3) * 8 + l8];
#pragma unroll
        for (int i = 0; i < 4; i++) {
            float4 hv = H4[(r0 + i) * 11 + kq];
            acc[i][0] += hv.x * w0.x; acc[i][1] += hv.x * w0.y;
            acc[i][2] += hv.x * w0.z; acc[i][3] += hv.x * w0.w;
            acc[i][0] += hv.y * w1.x; acc[i][1] += hv.y * w1.y;
            acc[i][2] += hv.y * w1.z; acc[i][3] += hv.y * w1.w;
            acc[i][0] += hv.z * w2.x; acc[i][1] += hv.z * w2.y;
            acc[i][2] += hv.z * w2.z; acc[i][3] += hv.z * w2.w;
            acc[i][0] += hv.w * w3.x; acc[i][1] += hv.w * w3.y;
            acc[i][2] += hv.w * w3.z; acc[i][3] += hv.w * w3.w;
        }
    }

    float4 alo = ((const float4*)a)[l8];
    float4 ahi = ((const float4*)a)[8 + l8];
#pragma unroll
    for (int i = 0; i < 4; i++) {
        int row = rowBase + r0 + i;
        if (row < N) {
            float4 zv = make_float4(acc[i][0], acc[i][1], acc[i][2], acc[i][3]);
            *(float4*)&z[(size_t)row * 32 + col4] = zv;
            float ps = zv.x * alo.x + zv.y * alo.y + zv.z * alo.z + zv.w * alo.w;
            float pd = zv.x * ahi.x + zv.y * ahi.y + zv.z * ahi.z + zv.w * ahi.w;
            ps += __shfl_xor(ps, 1, 64); ps += __shfl_xor(ps, 2, 64); ps += __shfl_xor(ps, 4, 64);
            pd += __shfl_xor(pd, 1, 64); pd += __shfl_xor(pd, 2, 64); pd += __shfl_xor(pd, 4, 64);
            if (l8 == 0) { s_src[row] = ps; s_dst[row] = pd; }
        }
    }
}

// layer 3: zs[i] = {z, z*a0} interleaved (single-line gather in agg1), s_dst sep.
__global__ __launch_bounds__(256) void gemm3_kernel(
    const float* __restrict__ h, const float* __restrict__ W,
    const float* __restrict__ a, float2* __restrict__ zs,
    float* __restrict__ s_dst, int N)
{
    int i = blockIdx.x * 256 + threadIdx.x;
    if (i >= N) return;
    const float4* hp = (const float4*)(h + (size_t)i * 32);
    const float4* wp = (const float4*)W;
    float acc = 0.f;
#pragma unroll
    for (int c = 0; c < 8; c++) {
        float4 v = hp[c];
        float4 w = wp[c];
        acc += v.x * w.x + v.y * w.y + v.z * w.z + v.w * w.w;
    }
    zs[i] = make_float2(acc, acc * a[0]);
    s_dst[i] = acc * a[1];
}

// ============================================================================
// CSR construction: linked list + fused degree count.
// hd[d] = {head (k+1 encoded, 0 = null), deg} — both atomics hit one line.
// ============================================================================

__global__ __launch_bounds__(256) void build_ll_deg_kernel(
    const int* __restrict__ src, const int* __restrict__ dst,
    int2* __restrict__ hd, int2* __restrict__ ll, int E)
{
    int k = blockIdx.x * 256 + threadIdx.x;
    if (k >= E) return;
    int d = dst[k];
    int s = src[k];
    int old = atomicExch(&hd[d].x, k + 1);
    atomicAdd(&hd[d].y, 1);
    ll[k] = make_int2(old, s);   // coalesced 8B store
}

__global__ __launch_bounds__(256) void scan1_kernel(
    const int2* __restrict__ hd, int* __restrict__ offsets,
    int* __restrict__ blockSums, int N)
{
    __shared__ int tmp[256];
    int tid = threadIdx.x;
    int i = blockIdx.x * 256 + tid;
    int v = (i < N) ? hd[i].y : 0;
    tmp[tid] = v;
    __syncthreads();
#pragma unroll
    for (int off = 1; off < 256; off <<= 1) {
        int t = (tid >= off) ? tmp[tid - off] : 0;
        __syncthreads();
        tmp[tid] += t;
        __syncthreads();
    }
    if (i < N) offsets[i] = tmp[tid];
    if (tid == 255) blockSums[blockIdx.x] = tmp[255];
}

__global__ __launch_bounds__(512) void scan2_kernel(int* __restrict__ blockSums, int nb)
{
    __shared__ int tmp[512];
    int tid = threadIdx.x;
    int v = (tid < nb) ? blockSums[tid] : 0;
    tmp[tid] = v;
    __syncthreads();
#pragma unroll
    for (int off = 1; off < 512; off <<= 1) {
        int t = (tid >= off) ? tmp[tid - off] : 0;
        __syncthreads();
        tmp[tid] += t;
        __syncthreads();
    }
    if (tid < nb) blockSums[tid] = tmp[tid] - v;
}

__global__ __launch_bounds__(256) void scan3_kernel(
    const int2* __restrict__ hd, const int* __restrict__ blockSums,
    int* __restrict__ offsets, int N, int E)
{
    int i = blockIdx.x * 256 + threadIdx.x;
    if (i < N) {
        offsets[i] = offsets[i] - hd[i].y + blockSums[i >> 8];
    }
    if (i == 0) offsets[N] = E;
}

__global__ __launch_bounds__(256) void walk_write_kernel(
    const int2* __restrict__ hd, const int2* __restrict__ ll,
    const int* __restrict__ offsets, int* __restrict__ csr_src, int N)
{
    int i = blockIdx.x * 256 + threadIdx.x;
    if (i >= N) return;
    int p = offsets[i];
    int e = hd[i].x;
    while (e > 0) {
        int2 v = ll[e - 1];
        csr_src[p++] = v.y;
        e = v.x;
    }
}

// ============================================================================
// Fused softmax + aggregation. 32-lane group per node.
// Phase A (edge-parallel): gather s_src, compute logits, reduce max & denom;
// e-values and src indices stay in registers (deg <= 128 fast path).
// Phase B (col-parallel): w & s broadcast via shuffles, coalesced z gather.
// ============================================================================

__global__ __launch_bounds__(256) void agg32_fused_kernel(
    const int* __restrict__ offsets, const int* __restrict__ csr_src,
    const float* __restrict__ s_src, const float* __restrict__ s_dst,
    const float* __restrict__ z, float* __restrict__ h, int N)
{
    int node = blockIdx.x * 8 + (threadIdx.x >> 5);
    int lane = threadIdx.x & 31;
    if (node >= N) return;

    int beg = offsets[node], end = offsets[node + 1];
    int deg = end - beg;
    float sd = s_dst[node];
    float o = 0.f;
    float rden;

    if (deg <= 128) {
        int   sreg[4];
        float ev[4];
        int nIter = (deg + 31) >> 5;
        float m = -3.0e38f;
#pragma unroll 4
        for (int it = 0; it < nIter; ++it) {
            int p = beg + it * 32 + lane;
            float e = -3.0e38f;
            int s = 0;
            if (p < end) {
                s = csr_src[p];
                e = s_src[s] + sd;
                e = (e > 0.f) ? e : NEG_SLOPE * e;
            }
            sreg[it] = s;
            ev[it] = e;
            m = fmaxf(m, e);
        }
#pragma unroll
        for (int off = 16; off > 0; off >>= 1) m = fmaxf(m, __shfl_xor(m, off, 32));

        float l = 0.f;
#pragma unroll 4
        for (int it = 0; it < nIter; ++it) {
            int p = beg + it * 32 + lane;
            float w = (p < end) ? __expf(ev[it] - m) : 0.f;
            ev[it] = w;
            l += w;
        }
#pragma unroll
        for (int off = 16; off > 0; off >>= 1) l += __shfl_xor(l, off, 32);
        rden = 1.f / fmaxf(l, 1e-9f);

        // phase B: accumulate over edges, w & s broadcast from registers
#pragma unroll 4
        for (int it = 0; it < nIter; ++it) {
            int pBase = beg + it * 32;
            int cnt = end - pBase; if (cnt > 32) cnt = 32;
            float wreg = ev[it];
            int   sv   = sreg[it];
            for (int j = 0; j < cnt; ++j) {
                float w = __shfl(wreg, j, 32);
                int   s = __shfl(sv,   j, 32);
                o += w * z[(size_t)s * 32 + lane];
            }
        }
    } else {
        // rare fallback: recompute path, no register caching
        float m = -3.0e38f;
        for (int p = beg + lane; p < end; p += 32) {
            float e = s_src[csr_src[p]] + sd;
            e = (e > 0.f) ? e : NEG_SLOPE * e;
            m = fmaxf(m, e);
        }
#pragma unroll
        for (int off = 16; off > 0; off >>= 1) m = fmaxf(m, __shfl_xor(m, off, 32));
        float l = 0.f;
        for (int p = beg + lane; p < end; p += 32) {
            float e = s_src[csr_src[p]] + sd;
            e = (e > 0.f) ? e : NEG_SLOPE * e;
            l += __expf(e - m);
        }
#pragma unroll
        for (int off = 16; off > 0; off >>= 1) l += __shfl_xor(l, off, 32);
        rden = 1.f / fmaxf(l, 1e-9f);
        for (int p = beg; p < end; ++p) {
            int s = csr_src[p];                    // uniform
            float e = s_src[s] + sd;
            e = (e > 0.f) ? e : NEG_SLOPE * e;
            float w = __expf(e - m);
            o += w * z[(size_t)s * 32 + lane];
        }
    }

    float v = o * rden;
    h[(size_t)node * 32 + lane] = (v > 0.f) ? v : 0.f;  // relu
}

// d_out = 1: fully edge-parallel, one 8B gather per edge, fused sigmoid
__global__ __launch_bounds__(256) void agg1_fused_kernel(
    const int* __restrict__ offsets, const int* __restrict__ csr_src,
    const float2* __restrict__ zs, const float* __restrict__ s_dst,
    float* __restrict__ out, int N)
{
    int node = blockIdx.x * 8 + (threadIdx.x >> 5);
    int lane = threadIdx.x & 31;
    if (node >= N) return;

    int beg = offsets[node], end = offsets[node + 1];
    int deg = end - beg;
    float sd = s_dst[node];

    if (deg <= 128) {
        float ev[4], zv[4];
        int nIter = (deg + 31) >> 5;
        float m = -3.0e38f;
#pragma unroll 4
        for (int it = 0; it < nIter; ++it) {
            int p = beg + it * 32 + lane;
            float e = -3.0e38f, zz = 0.f;
            if (p < end) {
                float2 v2 = zs[csr_src[p]];
                zz = v2.x;
                e = v2.y + sd;
                e = (e > 0.f) ? e : NEG_SLOPE * e;
            }
            ev[it] = e; zv[it] = zz;
            m = fmaxf(m, e);
        }
#pragma unroll
        for (int off = 16; off > 0; off >>= 1) m = fmaxf(m, __shfl_xor(m, off, 32));
        float l = 0.f, o = 0.f;
#pragma unroll 4
        for (int it = 0; it < nIter; ++it) {
            int p = beg + it * 32 + lane;
            float w = (p < end) ? __expf(ev[it] - m) : 0.f;
            l += w;
            o += w * zv[it];
        }
#pragma unroll
        for (int off = 16; off > 0; off >>= 1) {
            l += __shfl_xor(l, off, 32);
            o += __shfl_xor(o, off, 32);
        }
        if (lane == 0) {
            float v = o / fmaxf(l, 1e-9f);
            out[node] = 1.f / (1.f + __expf(-v));
        }
    } else {
        float m = -3.0e38f;
        for (int p = beg + lane; p < end; p += 32) {
            float e = zs[csr_src[p]].y + sd;
            e = (e > 0.f) ? e : NEG_SLOPE * e;
            m = fmaxf(m, e);
        }
#pragma unroll
        for (int off = 16; off > 0; off >>= 1) m = fmaxf(m, __shfl_xor(m, off, 32));
        float l = 0.f, o = 0.f;
        for (int p = beg + lane; p < end; p += 32) {
            float2 v2 = zs[csr_src[p]];
            float e = v2.y + sd;
            e = (e > 0.f) ? e : NEG_SLOPE * e;
            float w = __expf(e - m);
            l += w; o += w * v2.x;
        }
#pragma unroll
        for (int off = 16; off > 0; off >>= 1) {
            l += __shfl_xor(l, off, 32);
            o += __shfl_xor(o, off, 32);
        }
        if (lane == 0) {
            float v = o / fmaxf(l, 1e-9f);
            out[node] = 1.f / (1.f + __expf(-v));
        }
    }
}

// ============================================================================

extern "C" void kernel_launch(void* const* d_in, const int* in_sizes, int n_in,
                              void* d_out, int out_size, void* d_ws, size_t ws_size,
                              hipStream_t stream)
{
    const float* feature = (const float*)d_in[0];
    const int*   src     = (const int*)d_in[1];
    const int*   dst     = (const int*)d_in[2];
    const float* W1      = (const float*)d_in[3];
    const float* a1      = (const float*)d_in[4];
    const float* W2      = (const float*)d_in[5];
    const float* a2      = (const float*)d_in[6];
    const float* W3      = (const float*)d_in[7];
    const float* a3      = (const float*)d_in[8];
    float* out = (float*)d_out;

    const int N = in_sizes[0] / 128;
    const int E = in_sizes[1];

    // ---- workspace layout ----
    char* p = (char*)d_ws;
    float* zbuf    = (float*)p;  p += (size_t)N * 32 * sizeof(float);
    float* hbuf    = (float*)p;  p += (size_t)N * 32 * sizeof(float);
    float* s_src   = (float*)p;  p += (size_t)N * sizeof(float);
    float* s_dst   = (float*)p;  p += (size_t)N * sizeof(float);
    int2*  hd      = (int2*)p;   p += (size_t)N * sizeof(int2);
    int*   offsets = (int*)p;    p += ((size_t)N + 1) * sizeof(int);
    int*   blockSums = (int*)p;  p += 512 * sizeof(int);
    int2*  ll      = (int2*)p;   p += (size_t)E * sizeof(int2);
    int*   csr_src = (int*)p;    p += (size_t)E * sizeof(int);

    const int nodeBlocks8  = (N + 7) / 8;
    const int nodeBlocks   = (N + 255) / 256;
    const int edgeBlocks   = (E + 255) / 256;
    const int scanBlocks   = (N + 255) / 256;   // 391 for N=100000 (<=512)
    const int gemmBlocks64 = (N + 63) / 64;

    // ---- build CSR once: LL + fused degree, scan, sequential write ----
    hipMemsetAsync(hd, 0, (size_t)N * sizeof(int2), stream);  // head=0(null), deg=0
    hipLaunchKernelGGL(build_ll_deg_kernel, dim3(edgeBlocks), dim3(256), 0, stream,
                       src, dst, hd, ll, E);
    hipLaunchKernelGGL(scan1_kernel, dim3(scanBlocks), dim3(256), 0, stream,
                       hd, offsets, blockSums, N);
    hipLaunchKernelGGL(scan2_kernel, dim3(1), dim3(512), 0, stream,
                       blockSums, scanBlocks);
    hipLaunchKernelGGL(scan3_kernel, dim3(scanBlocks), dim3(256), 0, stream,
                       hd, blockSums, offsets, N, E);
    hipLaunchKernelGGL(walk_write_kernel, dim3(nodeBlocks), dim3(256), 0, stream,
                       hd, ll, offsets, csr_src, N);

    // ---- layer 1 (128 -> 32, relu) ----
    hipLaunchKernelGGL(gemm1_kernel, dim3(gemmBlocks64), dim3(128), 0, stream,
                       feature, W1, a1, zbuf, s_src, s_dst, N);
    hipLaunchKernelGGL(agg32_fused_kernel, dim3(nodeBlocks8), dim3(256), 0, stream,
                       offsets, csr_src, s_src, s_dst, zbuf, hbuf, N);

    // ---- layer 2 (32 -> 32, relu) ----
    hipLaunchKernelGGL(gemm2_kernel, dim3(gemmBlocks64), dim3(128), 0, stream,
                       hbuf, W2, a2, zbuf, s_src, s_dst, N);
    hipLaunchKernelGGL(agg32_fused_kernel, dim3(nodeBlocks8), dim3(256), 0, stream,
                       offsets, csr_src, s_src, s_dst, zbuf, hbuf, N);

    // ---- layer 3 (32 -> 1, sigmoid) ----
    float2* zs = (float2*)zbuf;
    hipLaunchKernelGGL(gemm3_kernel, dim3(nodeBlocks), dim3(256), 0, stream,
                       hbuf, W3, a3, zs, s_dst, N);
    hipLaunchKernelGGL(agg1_fused_kernel, dim3(nodeBlocks8), dim3(256), 0, stream,
                       offsets, csr_src, zs, s_dst, out, N);
}

// Round 7
// 436.081 us; speedup vs baseline: 1.1408x; 1.1408x over previous
//
#include <hip/hip_runtime.h>
#include <cstdint>
#include <cstddef>

#define NEG_SLOPE 0.01f

// ============================================================================
// GEMM kernels — register-blocked 4x4 micro-tiles, b128 LDS reads
// ============================================================================

__global__ __launch_bounds__(128) void gemm1_kernel(
    const float* __restrict__ h, const float* __restrict__ W,
    const float* __restrict__ a, float* __restrict__ z,
    float* __restrict__ s_src, float* __restrict__ s_dst, int N)
{
    __shared__ float Hl[64 * 140];
    __shared__ float Wl[128 * 32];
    int tid = threadIdx.x;
    int rowBase = blockIdx.x * 64;

    {
        const float4* W4 = (const float4*)W;
        float4* Wl4 = (float4*)Wl;
        for (int i = tid; i < 1024; i += 128) Wl4[i] = W4[i];
    }
    {
        const float4* h4 = (const float4*)h;
        for (int i = tid; i < 64 * 32; i += 128) {
            int r = i >> 5, kq = i & 31;
            float4 v = (rowBase + r < N) ? h4[(size_t)(rowBase + r) * 32 + kq]
                                         : make_float4(0.f, 0.f, 0.f, 0.f);
            *(float4*)&Hl[r * 140 + kq * 4] = v;
        }
    }
    __syncthreads();

    int wv   = tid >> 6;
    int lane = tid & 63;
    int g    = lane >> 3;
    int l8   = lane & 7;
    int r0   = wv * 32 + g * 4;
    int col4 = l8 * 4;

    float acc[4][4];
#pragma unroll
    for (int i = 0; i < 4; i++)
#pragma unroll
        for (int c = 0; c < 4; c++) acc[i][c] = 0.f;

    const float4* H4  = (const float4*)Hl;
    const float4* Wl4 = (const float4*)Wl;

#pragma unroll 2
    for (int kq = 0; kq < 32; kq++) {
        float4 w0 = Wl4[(kq * 4 + 0) * 8 + l8];
        float4 w1 = Wl4[(kq * 4 + 1) * 8 + l8];
        float4 w2 = Wl4[(kq * 4 + 2) * 8 + l8];
        float4 w3 = Wl4[(kq * 4 + 3) * 8 + l8];
#pragma unroll
        for (int i = 0; i < 4; i++) {
            float4 hv = H4[(r0 + i) * 35 + kq];
            acc[i][0] += hv.x * w0.x; acc[i][1] += hv.x * w0.y;
            acc[i][2] += hv.x * w0.z; acc[i][3] += hv.x * w0.w;
            acc[i][0] += hv.y * w1.x; acc[i][1] += hv.y * w1.y;
            acc[i][2] += hv.y * w1.z; acc[i][3] += hv.y * w1.w;
            acc[i][0] += hv.z * w2.x; acc[i][1] += hv.z * w2.y;
            acc[i][2] += hv.z * w2.z; acc[i][3] += hv.z * w2.w;
            acc[i][0] += hv.w * w3.x; acc[i][1] += hv.w * w3.y;
            acc[i][2] += hv.w * w3.z; acc[i][3] += hv.w * w3.w;
        }
    }

    float4 alo = ((const float4*)a)[l8];
    float4 ahi = ((const float4*)a)[8 + l8];
#pragma unroll
    for (int i = 0; i < 4; i++) {
        int row = rowBase + r0 + i;
        if (row < N) {
            float4 zv = make_float4(acc[i][0], acc[i][1], acc[i][2], acc[i][3]);
            *(float4*)&z[(size_t)row * 32 + col4] = zv;
            float ps = zv.x * alo.x + zv.y * alo.y + zv.z * alo.z + zv.w * alo.w;
            float pd = zv.x * ahi.x + zv.y * ahi.y + zv.z * ahi.z + zv.w * ahi.w;
            ps += __shfl_xor(ps, 1, 64); ps += __shfl_xor(ps, 2, 64); ps += __shfl_xor(ps, 4, 64);
            pd += __shfl_xor(pd, 1, 64); pd += __shfl_xor(pd, 2, 64); pd += __shfl_xor(pd, 4, 64);
            if (l8 == 0) { s_src[row] = ps; s_dst[row] = pd; }
        }
    }
}

__global__ __launch_bounds__(128) void gemm2_kernel(
    const float* __restrict__ h, const float* __restrict__ W,
    const float* __restrict__ a, float* __restrict__ z,
    float* __restrict__ s_src, float* __restrict__ s_dst, int N)
{
    __shared__ float Hl[64 * 44];
    __shared__ float Wl[32 * 32];
    int tid = threadIdx.x;
    int rowBase = blockIdx.x * 64;

    {
        const float4* W4 = (const float4*)W;
        float4* Wl4 = (float4*)Wl;
        for (int i = tid; i < 256; i += 128) Wl4[i] = W4[i];
    }
    {
        const float4* h4 = (const float4*)h;
        for (int i = tid; i < 64 * 8; i += 128) {
            int r = i >> 3, kq = i & 7;
            float4 v = (rowBase + r < N) ? h4[(size_t)(rowBase + r) * 8 + kq]
                                         : make_float4(0.f, 0.f, 0.f, 0.f);
            *(float4*)&Hl[r * 44 + kq * 4] = v;
        }
    }
    __syncthreads();

    int wv   = tid >> 6;
    int lane = tid & 63;
    int g    = lane >> 3;
    int l8   = lane & 7;
    int r0   = wv * 32 + g * 4;
    int col4 = l8 * 4;

    float acc[4][4];
#pragma unroll
    for (int i = 0; i < 4; i++)
#pragma unroll
        for (int c = 0; c < 4; c++) acc[i][c] = 0.f;

    const float4* H4  = (const float4*)Hl;
    const float4* Wl4 = (const float4*)Wl;

#pragma unroll
    for (int kq = 0; kq < 8; kq++) {
        float4 w0 = Wl4[(kq * 4 + 0) * 8 + l8];
        float4 w1 = Wl4[(kq * 4 + 1) * 8 + l8];
        float4 w2 = Wl4[(kq * 4 + 2) * 8 + l8];
        float4 w3 = Wl4[(kq * 4 + 3) * 8 + l8];
#pragma unroll
        for (int i = 0; i < 4; i++) {
            float4 hv = H4[(r0 + i) * 11 + kq];
            acc[i][0] += hv.x * w0.x; acc[i][1] += hv.x * w0.y;
            acc[i][2] += hv.x * w0.z; acc[i][3] += hv.x * w0.w;
            acc[i][0] += hv.y * w1.x; acc[i][1] += hv.y * w1.y;
            acc[i][2] += hv.y * w1.z; acc[i][3] += hv.y * w1.w;
            acc[i][0] += hv.z * w2.x; acc[i][1] += hv.z * w2.y;
            acc[i][2] += hv.z * w2.z; acc[i][3] += hv.z * w2.w;
            acc[i][0] += hv.w * w3.x; acc[i][1] += hv.w * w3.y;
            acc[i][2] += hv.w * w3.z; acc[i][3] += hv.w * w3.w;
        }
    }

    float4 alo = ((const float4*)a)[l8];
    float4 ahi = ((const float4*)a)[8 + l8];
#pragma unroll
    for (int i = 0; i < 4; i++) {
        int row = rowBase + r0 + i;
        if (row < N) {
            float4 zv = make_float4(acc[i][0], acc[i][1], acc[i][2], acc[i][3]);
            *(float4*)&z[(size_t)row * 32 + col4] = zv;
            float ps = zv.x * alo.x + zv.y * alo.y + zv.z * alo.z + zv.w * alo.w;
            float pd = zv.x * ahi.x + zv.y * ahi.y + zv.z * ahi.z + zv.w * ahi.w;
            ps += __shfl_xor(ps, 1, 64); ps += __shfl_xor(ps, 2, 64); ps += __shfl_xor(ps, 4, 64);
            pd += __shfl_xor(pd, 1, 64); pd += __shfl_xor(pd, 2, 64); pd += __shfl_xor(pd, 4, 64);
            if (l8 == 0) { s_src[row] = ps; s_dst[row] = pd; }
        }
    }
}

// layer 3: zs[i] = {z, z*a0} interleaved (single-line gather in agg1), s_dst sep.
__global__ __launch_bounds__(256) void gemm3_kernel(
    const float* __restrict__ h, const float* __restrict__ W,
    const float* __restrict__ a, float2* __restrict__ zs,
    float* __restrict__ s_dst, int N)
{
    int i = blockIdx.x * 256 + threadIdx.x;
    if (i >= N) return;
    const float4* hp = (const float4*)(h + (size_t)i * 32);
    const float4* wp = (const float4*)W;
    float acc = 0.f;
#pragma unroll
    for (int c = 0; c < 8; c++) {
        float4 v = hp[c];
        float4 w = wp[c];
        acc += v.x * w.x + v.y * w.y + v.z * w.z + v.w * w.w;
    }
    zs[i] = make_float2(acc, acc * a[0]);
    s_dst[i] = acc * a[1];
}

// ============================================================================
// CSR construction via per-dst linked list (single atomicExch per edge —
// NOTE: do NOT add a second atomic "on the same line": R6 showed device-scope
// atomics don't coalesce per-line; WRITE_SIZE doubled and build went 68->161us)
// ============================================================================

__global__ __launch_bounds__(256) void build_ll_kernel(
    const int* __restrict__ src, const int* __restrict__ dst,
    int* __restrict__ head, int2* __restrict__ ll, int E)
{
    int k = blockIdx.x * 256 + threadIdx.x;
    if (k >= E) return;
    int d = dst[k];
    int s = src[k];
    int old = atomicExch(&head[d], k);
    ll[k] = make_int2(old, s);   // coalesced 8B store
}

__global__ __launch_bounds__(256) void walk_count_kernel(
    const int* __restrict__ head, const int2* __restrict__ ll,
    int* __restrict__ deg, int N)
{
    int i = blockIdx.x * 256 + threadIdx.x;
    if (i >= N) return;
    int c = 0;
    int e = head[i];
    while (e >= 0) { c++; e = ll[e].x; }
    deg[i] = c;
}

__global__ __launch_bounds__(256) void scan1_kernel(
    const int* __restrict__ deg, int* __restrict__ offsets,
    int* __restrict__ blockSums, int N)
{
    __shared__ int tmp[256];
    int tid = threadIdx.x;
    int i = blockIdx.x * 256 + tid;
    int v = (i < N) ? deg[i] : 0;
    tmp[tid] = v;
    __syncthreads();
#pragma unroll
    for (int off = 1; off < 256; off <<= 1) {
        int t = (tid >= off) ? tmp[tid - off] : 0;
        __syncthreads();
        tmp[tid] += t;
        __syncthreads();
    }
    if (i < N) offsets[i] = tmp[tid];
    if (tid == 255) blockSums[blockIdx.x] = tmp[255];
}

__global__ __launch_bounds__(512) void scan2_kernel(int* __restrict__ blockSums, int nb)
{
    __shared__ int tmp[512];
    int tid = threadIdx.x;
    int v = (tid < nb) ? blockSums[tid] : 0;
    tmp[tid] = v;
    __syncthreads();
#pragma unroll
    for (int off = 1; off < 512; off <<= 1) {
        int t = (tid >= off) ? tmp[tid - off] : 0;
        __syncthreads();
        tmp[tid] += t;
        __syncthreads();
    }
    if (tid < nb) blockSums[tid] = tmp[tid] - v;
}

__global__ __launch_bounds__(256) void scan3_kernel(
    const int* __restrict__ deg, const int* __restrict__ blockSums,
    int* __restrict__ offsets, int N, int E)
{
    int i = blockIdx.x * 256 + threadIdx.x;
    if (i < N) {
        offsets[i] = offsets[i] - deg[i] + blockSums[i >> 8];
    }
    if (i == 0) offsets[N] = E;
}

__global__ __launch_bounds__(256) void walk_write_kernel(
    const int* __restrict__ head, const int2* __restrict__ ll,
    const int* __restrict__ offsets, int* __restrict__ csr_src, int N)
{
    int i = blockIdx.x * 256 + threadIdx.x;
    if (i >= N) return;
    int p = offsets[i];
    int e = head[i];
    while (e >= 0) {
        int2 v = ll[e];
        csr_src[p++] = v.y;
        e = v.x;
    }
}

// ============================================================================
// Fused softmax + aggregation. 32-lane group per node.
// ============================================================================

__global__ __launch_bounds__(256) void agg32_fused_kernel(
    const int* __restrict__ offsets, const int* __restrict__ csr_src,
    const float* __restrict__ s_src, const float* __restrict__ s_dst,
    const float* __restrict__ z, float* __restrict__ h, int N)
{
    int node = blockIdx.x * 8 + (threadIdx.x >> 5);
    int lane = threadIdx.x & 31;
    if (node >= N) return;

    int beg = offsets[node], end = offsets[node + 1];
    int deg = end - beg;
    float sd = s_dst[node];
    float o = 0.f;
    float rden;

    if (deg <= 128) {
        int   sreg[4];
        float ev[4];
        int nIter = (deg + 31) >> 5;
        float m = -3.0e38f;
#pragma unroll 4
        for (int it = 0; it < nIter; ++it) {
            int p = beg + it * 32 + lane;
            float e = -3.0e38f;
            int s = 0;
            if (p < end) {
                s = csr_src[p];
                e = s_src[s] + sd;
                e = (e > 0.f) ? e : NEG_SLOPE * e;
            }
            sreg[it] = s;
            ev[it] = e;
            m = fmaxf(m, e);
        }
#pragma unroll
        for (int off = 16; off > 0; off >>= 1) m = fmaxf(m, __shfl_xor(m, off, 32));

        float l = 0.f;
#pragma unroll 4
        for (int it = 0; it < nIter; ++it) {
            int p = beg + it * 32 + lane;
            float w = (p < end) ? __expf(ev[it] - m) : 0.f;
            ev[it] = w;
            l += w;
        }
#pragma unroll
        for (int off = 16; off > 0; off >>= 1) l += __shfl_xor(l, off, 32);
        rden = 1.f / fmaxf(l, 1e-9f);

#pragma unroll 4
        for (int it = 0; it < nIter; ++it) {
            int pBase = beg + it * 32;
            int cnt = end - pBase; if (cnt > 32) cnt = 32;
            float wreg = ev[it];
            int   sv   = sreg[it];
            for (int j = 0; j < cnt; ++j) {
                float w = __shfl(wreg, j, 32);
                int   s = __shfl(sv,   j, 32);
                o += w * z[(size_t)s * 32 + lane];
            }
        }
    } else {
        float m = -3.0e38f;
        for (int p = beg + lane; p < end; p += 32) {
            float e = s_src[csr_src[p]] + sd;
            e = (e > 0.f) ? e : NEG_SLOPE * e;
            m = fmaxf(m, e);
        }
#pragma unroll
        for (int off = 16; off > 0; off >>= 1) m = fmaxf(m, __shfl_xor(m, off, 32));
        float l = 0.f;
        for (int p = beg + lane; p < end; p += 32) {
            float e = s_src[csr_src[p]] + sd;
            e = (e > 0.f) ? e : NEG_SLOPE * e;
            l += __expf(e - m);
        }
#pragma unroll
        for (int off = 16; off > 0; off >>= 1) l += __shfl_xor(l, off, 32);
        rden = 1.f / fmaxf(l, 1e-9f);
        for (int p = beg; p < end; ++p) {
            int s = csr_src[p];                    // uniform
            float e = s_src[s] + sd;
            e = (e > 0.f) ? e : NEG_SLOPE * e;
            float w = __expf(e - m);
            o += w * z[(size_t)s * 32 + lane];
        }
    }

    float v = o * rden;
    h[(size_t)node * 32 + lane] = (v > 0.f) ? v : 0.f;  // relu
}

// d_out = 1: fully edge-parallel, one 8B gather per edge, fused sigmoid
__global__ __launch_bounds__(256) void agg1_fused_kernel(
    const int* __restrict__ offsets, const int* __restrict__ csr_src,
    const float2* __restrict__ zs, const float* __restrict__ s_dst,
    float* __restrict__ out, int N)
{
    int node = blockIdx.x * 8 + (threadIdx.x >> 5);
    int lane = threadIdx.x & 31;
    if (node >= N) return;

    int beg = offsets[node], end = offsets[node + 1];
    int deg = end - beg;
    float sd = s_dst[node];

    if (deg <= 128) {
        float ev[4], zv[4];
        int nIter = (deg + 31) >> 5;
        float m = -3.0e38f;
#pragma unroll 4
        for (int it = 0; it < nIter; ++it) {
            int p = beg + it * 32 + lane;
            float e = -3.0e38f, zz = 0.f;
            if (p < end) {
                float2 v2 = zs[csr_src[p]];
                zz = v2.x;
                e = v2.y + sd;
                e = (e > 0.f) ? e : NEG_SLOPE * e;
            }
            ev[it] = e; zv[it] = zz;
            m = fmaxf(m, e);
        }
#pragma unroll
        for (int off = 16; off > 0; off >>= 1) m = fmaxf(m, __shfl_xor(m, off, 32));
        float l = 0.f, o = 0.f;
#pragma unroll 4
        for (int it = 0; it < nIter; ++it) {
            int p = beg + it * 32 + lane;
            float w = (p < end) ? __expf(ev[it] - m) : 0.f;
            l += w;
            o += w * zv[it];
        }
#pragma unroll
        for (int off = 16; off > 0; off >>= 1) {
            l += __shfl_xor(l, off, 32);
            o += __shfl_xor(o, off, 32);
        }
        if (lane == 0) {
            float v = o / fmaxf(l, 1e-9f);
            out[node] = 1.f / (1.f + __expf(-v));
        }
    } else {
        float m = -3.0e38f;
        for (int p = beg + lane; p < end; p += 32) {
            float e = zs[csr_src[p]].y + sd;
            e = (e > 0.f) ? e : NEG_SLOPE * e;
            m = fmaxf(m, e);
        }
#pragma unroll
        for (int off = 16; off > 0; off >>= 1) m = fmaxf(m, __shfl_xor(m, off, 32));
        float l = 0.f, o = 0.f;
        for (int p = beg + lane; p < end; p += 32) {
            float2 v2 = zs[csr_src[p]];
            float e = v2.y + sd;
            e = (e > 0.f) ? e : NEG_SLOPE * e;
            float w = __expf(e - m);
            l += w; o += w * v2.x;
        }
#pragma unroll
        for (int off = 16; off > 0; off >>= 1) {
            l += __shfl_xor(l, off, 32);
            o += __shfl_xor(o, off, 32);
        }
        if (lane == 0) {
            float v = o / fmaxf(l, 1e-9f);
            out[node] = 1.f / (1.f + __expf(-v));
        }
    }
}

// ============================================================================

extern "C" void kernel_launch(void* const* d_in, const int* in_sizes, int n_in,
                              void* d_out, int out_size, void* d_ws, size_t ws_size,
                              hipStream_t stream)
{
    const float* feature = (const float*)d_in[0];
    const int*   src     = (const int*)d_in[1];
    const int*   dst     = (const int*)d_in[2];
    const float* W1      = (const float*)d_in[3];
    const float* a1      = (const float*)d_in[4];
    const float* W2      = (const float*)d_in[5];
    const float* a2      = (const float*)d_in[6];
    const float* W3      = (const float*)d_in[7];
    const float* a3      = (const float*)d_in[8];
    float* out = (float*)d_out;

    const int N = in_sizes[0] / 128;
    const int E = in_sizes[1];

    // ---- workspace layout ----
    char* p = (char*)d_ws;
    float* zbuf    = (float*)p;  p += (size_t)N * 32 * sizeof(float);
    float* hbuf    = (float*)p;  p += (size_t)N * 32 * sizeof(float);
    float* s_src   = (float*)p;  p += (size_t)N * sizeof(float);
    float* s_dst   = (float*)p;  p += (size_t)N * sizeof(float);
    int*   head    = (int*)p;    p += (size_t)N * sizeof(int);
    int*   deg     = (int*)p;    p += (size_t)N * sizeof(int);
    int*   offsets = (int*)p;    p += ((size_t)N + 1) * sizeof(int);
    int*   blockSums = (int*)p;  p += 512 * sizeof(int);
    int2*  ll      = (int2*)p;   p += (size_t)E * sizeof(int2);
    int*   csr_src = (int*)p;    p += (size_t)E * sizeof(int);

    const int nodeBlocks8  = (N + 7) / 8;
    const int nodeBlocks   = (N + 255) / 256;
    const int edgeBlocks   = (E + 255) / 256;
    const int scanBlocks   = (N + 255) / 256;   // 391 for N=100000 (<=512)
    const int gemmBlocks64 = (N + 63) / 64;

    // ---- build CSR once via linked list ----
    hipMemsetAsync(head, 0xFF, (size_t)N * sizeof(int), stream);   // head = -1
    hipLaunchKernelGGL(build_ll_kernel, dim3(edgeBlocks), dim3(256), 0, stream,
                       src, dst, head, ll, E);
    hipLaunchKernelGGL(walk_count_kernel, dim3(nodeBlocks), dim3(256), 0, stream,
                       head, ll, deg, N);
    hipLaunchKernelGGL(scan1_kernel, dim3(scanBlocks), dim3(256), 0, stream,
                       deg, offsets, blockSums, N);
    hipLaunchKernelGGL(scan2_kernel, dim3(1), dim3(512), 0, stream,
                       blockSums, scanBlocks);
    hipLaunchKernelGGL(scan3_kernel, dim3(scanBlocks), dim3(256), 0, stream,
                       deg, blockSums, offsets, N, E);
    hipLaunchKernelGGL(walk_write_kernel, dim3(nodeBlocks), dim3(256), 0, stream,
                       head, ll, offsets, csr_src, N);

    // ---- layer 1 (128 -> 32, relu) ----
    hipLaunchKernelGGL(gemm1_kernel, dim3(gemmBlocks64), dim3(128), 0, stream,
                       feature, W1, a1, zbuf, s_src, s_dst, N);
    hipLaunchKernelGGL(agg32_fused_kernel, dim3(nodeBlocks8), dim3(256), 0, stream,
                       offsets, csr_src, s_src, s_dst, zbuf, hbuf, N);

    // ---- layer 2 (32 -> 32, relu) ----
    hipLaunchKernelGGL(gemm2_kernel, dim3(gemmBlocks64), dim3(128), 0, stream,
                       hbuf, W2, a2, zbuf, s_src, s_dst, N);
    hipLaunchKernelGGL(agg32_fused_kernel, dim3(nodeBlocks8), dim3(256), 0, stream,
                       offsets, csr_src, s_src, s_dst, zbuf, hbuf, N);

    // ---- layer 3 (32 -> 1, sigmoid) ----
    float2* zs = (float2*)zbuf;
    hipLaunchKernelGGL(gemm3_kernel, dim3(nodeBlocks), dim3(256), 0, stream,
                       hbuf, W3, a3, zs, s_dst, N);
    hipLaunchKernelGGL(agg1_fused_kernel, dim3(nodeBlocks8), dim3(256), 0, stream,
                       offsets, csr_src, zs, s_dst, out, N);
}

// Round 8
// 349.377 us; speedup vs baseline: 1.4238x; 1.2482x over previous
//
#include <hip/hip_runtime.h>
#include <cstdint>
#include <cstddef>

#define NEG_SLOPE 0.01f

// ============================================================================
// GEMM kernels — register-blocked 4x4 micro-tiles, b128 LDS reads
// ============================================================================

__global__ __launch_bounds__(128) void gemm1_kernel(
    const float* __restrict__ h, const float* __restrict__ W,
    const float* __restrict__ a, float* __restrict__ z,
    float* __restrict__ s_src, float* __restrict__ s_dst, int N)
{
    __shared__ float Hl[64 * 140];
    __shared__ float Wl[128 * 32];
    int tid = threadIdx.x;
    int rowBase = blockIdx.x * 64;

    {
        const float4* W4 = (const float4*)W;
        float4* Wl4 = (float4*)Wl;
        for (int i = tid; i < 1024; i += 128) Wl4[i] = W4[i];
    }
    {
        const float4* h4 = (const float4*)h;
        for (int i = tid; i < 64 * 32; i += 128) {
            int r = i >> 5, kq = i & 31;
            float4 v = (rowBase + r < N) ? h4[(size_t)(rowBase + r) * 32 + kq]
                                         : make_float4(0.f, 0.f, 0.f, 0.f);
            *(float4*)&Hl[r * 140 + kq * 4] = v;
        }
    }
    __syncthreads();

    int wv   = tid >> 6;
    int lane = tid & 63;
    int g    = lane >> 3;
    int l8   = lane & 7;
    int r0   = wv * 32 + g * 4;
    int col4 = l8 * 4;

    float acc[4][4];
#pragma unroll
    for (int i = 0; i < 4; i++)
#pragma unroll
        for (int c = 0; c < 4; c++) acc[i][c] = 0.f;

    const float4* H4  = (const float4*)Hl;
    const float4* Wl4 = (const float4*)Wl;

#pragma unroll 2
    for (int kq = 0; kq < 32; kq++) {
        float4 w0 = Wl4[(kq * 4 + 0) * 8 + l8];
        float4 w1 = Wl4[(kq * 4 + 1) * 8 + l8];
        float4 w2 = Wl4[(kq * 4 + 2) * 8 + l8];
        float4 w3 = Wl4[(kq * 4 + 3) * 8 + l8];
#pragma unroll
        for (int i = 0; i < 4; i++) {
            float4 hv = H4[(r0 + i) * 35 + kq];
            acc[i][0] += hv.x * w0.x; acc[i][1] += hv.x * w0.y;
            acc[i][2] += hv.x * w0.z; acc[i][3] += hv.x * w0.w;
            acc[i][0] += hv.y * w1.x; acc[i][1] += hv.y * w1.y;
            acc[i][2] += hv.y * w1.z; acc[i][3] += hv.y * w1.w;
            acc[i][0] += hv.z * w2.x; acc[i][1] += hv.z * w2.y;
            acc[i][2] += hv.z * w2.z; acc[i][3] += hv.z * w2.w;
            acc[i][0] += hv.w * w3.x; acc[i][1] += hv.w * w3.y;
            acc[i][2] += hv.w * w3.z; acc[i][3] += hv.w * w3.w;
        }
    }

    float4 alo = ((const float4*)a)[l8];
    float4 ahi = ((const float4*)a)[8 + l8];
#pragma unroll
    for (int i = 0; i < 4; i++) {
        int row = rowBase + r0 + i;
        if (row < N) {
            float4 zv = make_float4(acc[i][0], acc[i][1], acc[i][2], acc[i][3]);
            *(float4*)&z[(size_t)row * 32 + col4] = zv;
            float ps = zv.x * alo.x + zv.y * alo.y + zv.z * alo.z + zv.w * alo.w;
            float pd = zv.x * ahi.x + zv.y * ahi.y + zv.z * ahi.z + zv.w * ahi.w;
            ps += __shfl_xor(ps, 1, 64); ps += __shfl_xor(ps, 2, 64); ps += __shfl_xor(ps, 4, 64);
            pd += __shfl_xor(pd, 1, 64); pd += __shfl_xor(pd, 2, 64); pd += __shfl_xor(pd, 4, 64);
            if (l8 == 0) { s_src[row] = ps; s_dst[row] = pd; }
        }
    }
}

__global__ __launch_bounds__(128) void gemm2_kernel(
    const float* __restrict__ h, const float* __restrict__ W,
    const float* __restrict__ a, float* __restrict__ z,
    float* __restrict__ s_src, float* __restrict__ s_dst, int N)
{
    __shared__ float Hl[64 * 44];
    __shared__ float Wl[32 * 32];
    int tid = threadIdx.x;
    int rowBase = blockIdx.x * 64;

    {
        const float4* W4 = (const float4*)W;
        float4* Wl4 = (float4*)Wl;
        for (int i = tid; i < 256; i += 128) Wl4[i] = W4[i];
    }
    {
        const float4* h4 = (const float4*)h;
        for (int i = tid; i < 64 * 8; i += 128) {
            int r = i >> 3, kq = i & 7;
            float4 v = (rowBase + r < N) ? h4[(size_t)(rowBase + r) * 8 + kq]
                                         : make_float4(0.f, 0.f, 0.f, 0.f);
            *(float4*)&Hl[r * 44 + kq * 4] = v;
        }
    }
    __syncthreads();

    int wv   = tid >> 6;
    int lane = tid & 63;
    int g    = lane >> 3;
    int l8   = lane & 7;
    int r0   = wv * 32 + g * 4;
    int col4 = l8 * 4;

    float acc[4][4];
#pragma unroll
    for (int i = 0; i < 4; i++)
#pragma unroll
        for (int c = 0; c < 4; c++) acc[i][c] = 0.f;

    const float4* H4  = (const float4*)Hl;
    const float4* Wl4 = (const float4*)Wl;

#pragma unroll
    for (int kq = 0; kq < 8; kq++) {
        float4 w0 = Wl4[(kq * 4 + 0) * 8 + l8];
        float4 w1 = Wl4[(kq * 4 + 1) * 8 + l8];
        float4 w2 = Wl4[(kq * 4 + 2) * 8 + l8];
        float4 w3 = Wl4[(kq * 4 + 3) * 8 + l8];
#pragma unroll
        for (int i = 0; i < 4; i++) {
            float4 hv = H4[(r0 + i) * 11 + kq];
            acc[i][0] += hv.x * w0.x; acc[i][1] += hv.x * w0.y;
            acc[i][2] += hv.x * w0.z; acc[i][3] += hv.x * w0.w;
            acc[i][0] += hv.y * w1.x; acc[i][1] += hv.y * w1.y;
            acc[i][2] += hv.y * w1.z; acc[i][3] += hv.y * w1.w;
            acc[i][0] += hv.z * w2.x; acc[i][1] += hv.z * w2.y;
            acc[i][2] += hv.z * w2.z; acc[i][3] += hv.z * w2.w;
            acc[i][0] += hv.w * w3.x; acc[i][1] += hv.w * w3.y;
            acc[i][2] += hv.w * w3.z; acc[i][3] += hv.w * w3.w;
        }
    }

    float4 alo = ((const float4*)a)[l8];
    float4 ahi = ((const float4*)a)[8 + l8];
#pragma unroll
    for (int i = 0; i < 4; i++) {
        int row = rowBase + r0 + i;
        if (row < N) {
            float4 zv = make_float4(acc[i][0], acc[i][1], acc[i][2], acc[i][3]);
            *(float4*)&z[(size_t)row * 32 + col4] = zv;
            float ps = zv.x * alo.x + zv.y * alo.y + zv.z * alo.z + zv.w * alo.w;
            float pd = zv.x * ahi.x + zv.y * ahi.y + zv.z * ahi.z + zv.w * ahi.w;
            ps += __shfl_xor(ps, 1, 64); ps += __shfl_xor(ps, 2, 64); ps += __shfl_xor(ps, 4, 64);
            pd += __shfl_xor(pd, 1, 64); pd += __shfl_xor(pd, 2, 64); pd += __shfl_xor(pd, 4, 64);
            if (l8 == 0) { s_src[row] = ps; s_dst[row] = pd; }
        }
    }
}

// layer 3: zs[i] = {z, z*a0} interleaved (single-line gather in agg1), s_dst sep.
__global__ __launch_bounds__(256) void gemm3_kernel(
    const float* __restrict__ h, const float* __restrict__ W,
    const float* __restrict__ a, float2* __restrict__ zs,
    float* __restrict__ s_dst, int N)
{
    int i = blockIdx.x * 256 + threadIdx.x;
    if (i >= N) return;
    const float4* hp = (const float4*)(h + (size_t)i * 32);
    const float4* wp = (const float4*)W;
    float acc = 0.f;
#pragma unroll
    for (int c = 0; c < 8; c++) {
        float4 v = hp[c];
        float4 w = wp[c];
        acc += v.x * w.x + v.y * w.y + v.z * w.z + v.w * w.w;
    }
    zs[i] = make_float2(acc, acc * a[0]);
    s_dst[i] = acc * a[1];
}

// ============================================================================
// Atomic-free CSR build: two-level counting sort by dst.
// (R6 lesson: device-scope atomics cost a 32B fabric RMW each — 1.6M of them
// was 80+us. This path uses ONLY LDS atomics.)
// Bucket = dst >> 8 (256 nodes/bucket). Tiles of 4096 edges.
// ============================================================================

#define TILE_E 4096
#define NB_MAX 512     // supports N <= 131072

// Pass A: per-tile histogram over buckets -> counts[b*TB + t]
__global__ __launch_bounds__(256) void csr_hist_kernel(
    const int* __restrict__ dst, int* __restrict__ counts,
    int E, int TB, int NB)
{
    __shared__ int hist[NB_MAX];
    int tid = threadIdx.x;
    int t = blockIdx.x;
    for (int b = tid; b < NB; b += 256) hist[b] = 0;
    __syncthreads();
    int base = t * TILE_E;
    for (int i = tid; i < TILE_E; i += 256) {
        int k = base + i;
        if (k < E) atomicAdd(&hist[dst[k] >> 8], 1);
    }
    __syncthreads();
    for (int b = tid; b < NB; b += 256) counts[b * TB + t] = hist[b];
}

// scan phase 1: per-block inclusive scan + block totals (generic length M)
__global__ __launch_bounds__(256) void scan1_kernel(
    const int* __restrict__ vals, int* __restrict__ incl,
    int* __restrict__ blockSums, int M)
{
    __shared__ int tmp[256];
    int tid = threadIdx.x;
    int i = blockIdx.x * 256 + tid;
    int v = (i < M) ? vals[i] : 0;
    tmp[tid] = v;
    __syncthreads();
#pragma unroll
    for (int off = 1; off < 256; off <<= 1) {
        int t = (tid >= off) ? tmp[tid - off] : 0;
        __syncthreads();
        tmp[tid] += t;
        __syncthreads();
    }
    if (i < M) incl[i] = tmp[tid];
    if (tid == 255) blockSums[blockIdx.x] = tmp[255];
}

// scan phase 2: single 1024-thread block exclusive-scans blockSums (nb <= 1024)
__global__ __launch_bounds__(1024) void scan2_kernel(int* __restrict__ blockSums, int nb)
{
    __shared__ int tmp[1024];
    int tid = threadIdx.x;
    int v = (tid < nb) ? blockSums[tid] : 0;
    tmp[tid] = v;
    __syncthreads();
#pragma unroll
    for (int off = 1; off < 1024; off <<= 1) {
        int t = (tid >= off) ? tmp[tid - off] : 0;
        __syncthreads();
        tmp[tid] += t;
        __syncthreads();
    }
    if (tid < nb) blockSums[tid] = tmp[tid] - v;  // exclusive
}

// scan phase 3: inclusive -> exclusive in place; cscan[M] = E
__global__ __launch_bounds__(256) void scan3_kernel(
    const int* __restrict__ vals, const int* __restrict__ blockSums,
    int* __restrict__ cscan, int M, int E)
{
    int i = blockIdx.x * 256 + threadIdx.x;
    if (i < M) {
        cscan[i] = cscan[i] - vals[i] + blockSums[i >> 8];
    }
    if (i == 0) cscan[M] = E;
}

// Pass B: scatter edges into bucket-contiguous ebuf as {src, dst&255}
__global__ __launch_bounds__(256) void csr_scatter_kernel(
    const int* __restrict__ src, const int* __restrict__ dst,
    const int* __restrict__ cscan, int2* __restrict__ ebuf,
    int E, int TB, int NB)
{
    __shared__ int baseB[NB_MAX];
    __shared__ int cur[NB_MAX];
    int tid = threadIdx.x;
    int t = blockIdx.x;
    for (int b = tid; b < NB; b += 256) {
        baseB[b] = cscan[b * TB + t];
        cur[b] = 0;
    }
    __syncthreads();
    int base = t * TILE_E;
    for (int i = tid; i < TILE_E; i += 256) {
        int k = base + i;
        if (k < E) {
            int d = dst[k], s = src[k];
            int b = d >> 8;
            int r = atomicAdd(&cur[b], 1);
            ebuf[baseB[b] + r] = make_int2(s, d & 255);
        }
    }
}

// Pass 2: per-bucket local counting sort -> csr_src + offsets
__global__ __launch_bounds__(256) void csr_bucket_kernel(
    const int2* __restrict__ ebuf, const int* __restrict__ cscan,
    int* __restrict__ csr_src, int* __restrict__ offsets,
    int N, int E, int TB)
{
    __shared__ int2 eb[6144];     // 48KB staging
    __shared__ int hist[256];
    __shared__ int loff[256];
    __shared__ int tmp[256];
    int tid = threadIdx.x;
    int b = blockIdx.x;

    int beg = cscan[b * TB];
    int endv = cscan[(b + 1) * TB];   // cscan[M] == E covers the last bucket
    int cnt = endv - beg;
    int first = b << 8;

    hist[tid] = 0;
    __syncthreads();

    bool inLds = (cnt <= 6144);
    for (int i = tid; i < cnt; i += 256) {
        int2 v = ebuf[beg + i];
        if (inLds) eb[i] = v;
        atomicAdd(&hist[v.y], 1);
    }
    __syncthreads();

    // exclusive scan of hist[256]
    int hv = hist[tid];
    tmp[tid] = hv;
    __syncthreads();
#pragma unroll
    for (int off = 1; off < 256; off <<= 1) {
        int t = (tid >= off) ? tmp[tid - off] : 0;
        __syncthreads();
        tmp[tid] += t;
        __syncthreads();
    }
    loff[tid] = tmp[tid] - hv;
    __syncthreads();

    // write node offsets (covers all nodes incl. deg-0)
    if (first + tid < N) offsets[first + tid] = beg + loff[tid];
    if (b == 0 && tid == 0) offsets[N] = E;

    // reuse hist as cursor
    hist[tid] = 0;
    __syncthreads();

    for (int i = tid; i < cnt; i += 256) {
        int2 v = inLds ? eb[i] : ebuf[beg + i];
        int r = atomicAdd(&hist[v.y], 1);
        csr_src[beg + loff[v.y] + r] = v.x;
    }
}

// ============================================================================
// Fused softmax + aggregation. 32-lane group per node.
// ============================================================================

__global__ __launch_bounds__(256) void agg32_fused_kernel(
    const int* __restrict__ offsets, const int* __restrict__ csr_src,
    const float* __restrict__ s_src, const float* __restrict__ s_dst,
    const float* __restrict__ z, float* __restrict__ h, int N)
{
    int node = blockIdx.x * 8 + (threadIdx.x >> 5);
    int lane = threadIdx.x & 31;
    if (node >= N) return;

    int beg = offsets[node], end = offsets[node + 1];
    int deg = end - beg;
    float sd = s_dst[node];
    float o = 0.f;
    float rden;

    if (deg <= 128) {
        int   sreg[4];
        float ev[4];
        int nIter = (deg + 31) >> 5;
        float m = -3.0e38f;
#pragma unroll 4
        for (int it = 0; it < nIter; ++it) {
            int p = beg + it * 32 + lane;
            float e = -3.0e38f;
            int s = 0;
            if (p < end) {
                s = csr_src[p];
                e = s_src[s] + sd;
                e = (e > 0.f) ? e : NEG_SLOPE * e;
            }
            sreg[it] = s;
            ev[it] = e;
            m = fmaxf(m, e);
        }
#pragma unroll
        for (int off = 16; off > 0; off >>= 1) m = fmaxf(m, __shfl_xor(m, off, 32));

        float l = 0.f;
#pragma unroll 4
        for (int it = 0; it < nIter; ++it) {
            int p = beg + it * 32 + lane;
            float w = (p < end) ? __expf(ev[it] - m) : 0.f;
            ev[it] = w;
            l += w;
        }
#pragma unroll
        for (int off = 16; off > 0; off >>= 1) l += __shfl_xor(l, off, 32);
        rden = 1.f / fmaxf(l, 1e-9f);

#pragma unroll 4
        for (int it = 0; it < nIter; ++it) {
            int pBase = beg + it * 32;
            int cnt = end - pBase; if (cnt > 32) cnt = 32;
            float wreg = ev[it];
            int   sv   = sreg[it];
            for (int j = 0; j < cnt; ++j) {
                float w = __shfl(wreg, j, 32);
                int   s = __shfl(sv,   j, 32);
                o += w * z[(size_t)s * 32 + lane];
            }
        }
    } else {
        float m = -3.0e38f;
        for (int p = beg + lane; p < end; p += 32) {
            float e = s_src[csr_src[p]] + sd;
            e = (e > 0.f) ? e : NEG_SLOPE * e;
            m = fmaxf(m, e);
        }
#pragma unroll
        for (int off = 16; off > 0; off >>= 1) m = fmaxf(m, __shfl_xor(m, off, 32));
        float l = 0.f;
        for (int p = beg + lane; p < end; p += 32) {
            float e = s_src[csr_src[p]] + sd;
            e = (e > 0.f) ? e : NEG_SLOPE * e;
            l += __expf(e - m);
        }
#pragma unroll
        for (int off = 16; off > 0; off >>= 1) l += __shfl_xor(l, off, 32);
        rden = 1.f / fmaxf(l, 1e-9f);
        for (int p = beg; p < end; ++p) {
            int s = csr_src[p];                    // uniform
            float e = s_src[s] + sd;
            e = (e > 0.f) ? e : NEG_SLOPE * e;
            float w = __expf(e - m);
            o += w * z[(size_t)s * 32 + lane];
        }
    }

    float v = o * rden;
    h[(size_t)node * 32 + lane] = (v > 0.f) ? v : 0.f;  // relu
}

// d_out = 1: fully edge-parallel, one 8B gather per edge, fused sigmoid
__global__ __launch_bounds__(256) void agg1_fused_kernel(
    const int* __restrict__ offsets, const int* __restrict__ csr_src,
    const float2* __restrict__ zs, const float* __restrict__ s_dst,
    float* __restrict__ out, int N)
{
    int node = blockIdx.x * 8 + (threadIdx.x >> 5);
    int lane = threadIdx.x & 31;
    if (node >= N) return;

    int beg = offsets[node], end = offsets[node + 1];
    int deg = end - beg;
    float sd = s_dst[node];

    if (deg <= 128) {
        float ev[4], zv[4];
        int nIter = (deg + 31) >> 5;
        float m = -3.0e38f;
#pragma unroll 4
        for (int it = 0; it < nIter; ++it) {
            int p = beg + it * 32 + lane;
            float e = -3.0e38f, zz = 0.f;
            if (p < end) {
                float2 v2 = zs[csr_src[p]];
                zz = v2.x;
                e = v2.y + sd;
                e = (e > 0.f) ? e : NEG_SLOPE * e;
            }
            ev[it] = e; zv[it] = zz;
            m = fmaxf(m, e);
        }
#pragma unroll
        for (int off = 16; off > 0; off >>= 1) m = fmaxf(m, __shfl_xor(m, off, 32));
        float l = 0.f, o = 0.f;
#pragma unroll 4
        for (int it = 0; it < nIter; ++it) {
            int p = beg + it * 32 + lane;
            float w = (p < end) ? __expf(ev[it] - m) : 0.f;
            l += w;
            o += w * zv[it];
        }
#pragma unroll
        for (int off = 16; off > 0; off >>= 1) {
            l += __shfl_xor(l, off, 32);
            o += __shfl_xor(o, off, 32);
        }
        if (lane == 0) {
            float v = o / fmaxf(l, 1e-9f);
            out[node] = 1.f / (1.f + __expf(-v));
        }
    } else {
        float m = -3.0e38f;
        for (int p = beg + lane; p < end; p += 32) {
            float e = zs[csr_src[p]].y + sd;
            e = (e > 0.f) ? e : NEG_SLOPE * e;
            m = fmaxf(m, e);
        }
#pragma unroll
        for (int off = 16; off > 0; off >>= 1) m = fmaxf(m, __shfl_xor(m, off, 32));
        float l = 0.f, o = 0.f;
        for (int p = beg + lane; p < end; p += 32) {
            float2 v2 = zs[csr_src[p]];
            float e = v2.y + sd;
            e = (e > 0.f) ? e : NEG_SLOPE * e;
            float w = __expf(e - m);
            l += w; o += w * v2.x;
        }
#pragma unroll
        for (int off = 16; off > 0; off >>= 1) {
            l += __shfl_xor(l, off, 32);
            o += __shfl_xor(o, off, 32);
        }
        if (lane == 0) {
            float v = o / fmaxf(l, 1e-9f);
            out[node] = 1.f / (1.f + __expf(-v));
        }
    }
}

// ============================================================================

extern "C" void kernel_launch(void* const* d_in, const int* in_sizes, int n_in,
                              void* d_out, int out_size, void* d_ws, size_t ws_size,
                              hipStream_t stream)
{
    const float* feature = (const float*)d_in[0];
    const int*   src     = (const int*)d_in[1];
    const int*   dst     = (const int*)d_in[2];
    const float* W1      = (const float*)d_in[3];
    const float* a1      = (const float*)d_in[4];
    const float* W2      = (const float*)d_in[5];
    const float* a2      = (const float*)d_in[6];
    const float* W3      = (const float*)d_in[7];
    const float* a3      = (const float*)d_in[8];
    float* out = (float*)d_out;

    const int N = in_sizes[0] / 128;
    const int E = in_sizes[1];

    const int TB = (E + TILE_E - 1) / TILE_E;     // edge tiles (391)
    const int NB = (N + 255) >> 8;                // buckets (391)
    const int M  = NB * TB;                       // counts length (152881)

    // ---- workspace layout ----
    char* p = (char*)d_ws;
    float* zbuf    = (float*)p;  p += (size_t)N * 32 * sizeof(float);
    float* hbuf    = (float*)p;  p += (size_t)N * 32 * sizeof(float);
    float* s_src   = (float*)p;  p += (size_t)N * sizeof(float);
    float* s_dst   = (float*)p;  p += (size_t)N * sizeof(float);
    int*   offsets = (int*)p;    p += ((size_t)N + 1) * sizeof(int);
    int*   counts  = (int*)p;    p += ((size_t)M + 1) * sizeof(int);
    int*   cscan   = (int*)p;    p += ((size_t)M + 1) * sizeof(int);
    int*   blockSums = (int*)p;  p += 1024 * sizeof(int);
    int2*  ebuf    = (int2*)p;   p += (size_t)E * sizeof(int2);
    int*   csr_src = (int*)p;    p += (size_t)E * sizeof(int);

    const int nodeBlocks8  = (N + 7) / 8;
    const int nodeBlocks   = (N + 255) / 256;
    const int gemmBlocks64 = (N + 63) / 64;
    const int scanBlocksM  = (M + 255) / 256;     // 598 (<= 1024 for scan2)

    // ---- build CSR: atomic-free two-level counting sort ----
    hipLaunchKernelGGL(csr_hist_kernel, dim3(TB), dim3(256), 0, stream,
                       dst, counts, E, TB, NB);
    hipLaunchKernelGGL(scan1_kernel, dim3(scanBlocksM), dim3(256), 0, stream,
                       counts, cscan, blockSums, M);
    hipLaunchKernelGGL(scan2_kernel, dim3(1), dim3(1024), 0, stream,
                       blockSums, scanBlocksM);
    hipLaunchKernelGGL(scan3_kernel, dim3(scanBlocksM), dim3(256), 0, stream,
                       counts, blockSums, cscan, M, E);
    hipLaunchKernelGGL(csr_scatter_kernel, dim3(TB), dim3(256), 0, stream,
                       src, dst, cscan, ebuf, E, TB, NB);
    hipLaunchKernelGGL(csr_bucket_kernel, dim3(NB), dim3(256), 0, stream,
                       ebuf, cscan, csr_src, offsets, N, E, TB);

    // ---- layer 1 (128 -> 32, relu) ----
    hipLaunchKernelGGL(gemm1_kernel, dim3(gemmBlocks64), dim3(128), 0, stream,
                       feature, W1, a1, zbuf, s_src, s_dst, N);
    hipLaunchKernelGGL(agg32_fused_kernel, dim3(nodeBlocks8), dim3(256), 0, stream,
                       offsets, csr_src, s_src, s_dst, zbuf, hbuf, N);

    // ---- layer 2 (32 -> 32, relu) ----
    hipLaunchKernelGGL(gemm2_kernel, dim3(gemmBlocks64), dim3(128), 0, stream,
                       hbuf, W2, a2, zbuf, s_src, s_dst, N);
    hipLaunchKernelGGL(agg32_fused_kernel, dim3(nodeBlocks8), dim3(256), 0, stream,
                       offsets, csr_src, s_src, s_dst, zbuf, hbuf, N);

    // ---- layer 3 (32 -> 1, sigmoid) ----
    float2* zs = (float2*)zbuf;
    hipLaunchKernelGGL(gemm3_kernel, dim3(nodeBlocks), dim3(256), 0, stream,
                       hbuf, W3, a3, zs, s_dst, N);
    hipLaunchKernelGGL(agg1_fused_kernel, dim3(nodeBlocks8), dim3(256), 0, stream,
                       offsets, csr_src, zs, s_dst, out, N);
}

// Round 9
// 298.218 us; speedup vs baseline: 1.6681x; 1.1715x over previous
//
#include <hip/hip_runtime.h>
#include <cstdint>
#include <cstddef>

#define NEG_SLOPE 0.01f

// ============================================================================
// GEMM kernels — register-blocked 4x4 micro-tiles, b128 LDS reads
// ============================================================================

__global__ __launch_bounds__(128) void gemm1_kernel(
    const float* __restrict__ h, const float* __restrict__ W,
    const float* __restrict__ a, float* __restrict__ z,
    float* __restrict__ s_src, float* __restrict__ s_dst, int N)
{
    __shared__ float Hl[64 * 140];
    __shared__ float Wl[128 * 32];
    int tid = threadIdx.x;
    int rowBase = blockIdx.x * 64;

    {
        const float4* W4 = (const float4*)W;
        float4* Wl4 = (float4*)Wl;
        for (int i = tid; i < 1024; i += 128) Wl4[i] = W4[i];
    }
    {
        const float4* h4 = (const float4*)h;
        for (int i = tid; i < 64 * 32; i += 128) {
            int r = i >> 5, kq = i & 31;
            float4 v = (rowBase + r < N) ? h4[(size_t)(rowBase + r) * 32 + kq]
                                         : make_float4(0.f, 0.f, 0.f, 0.f);
            *(float4*)&Hl[r * 140 + kq * 4] = v;
        }
    }
    __syncthreads();

    int wv   = tid >> 6;
    int lane = tid & 63;
    int g    = lane >> 3;
    int l8   = lane & 7;
    int r0   = wv * 32 + g * 4;
    int col4 = l8 * 4;

    float acc[4][4];
#pragma unroll
    for (int i = 0; i < 4; i++)
#pragma unroll
        for (int c = 0; c < 4; c++) acc[i][c] = 0.f;

    const float4* H4  = (const float4*)Hl;
    const float4* Wl4 = (const float4*)Wl;

#pragma unroll 2
    for (int kq = 0; kq < 32; kq++) {
        float4 w0 = Wl4[(kq * 4 + 0) * 8 + l8];
        float4 w1 = Wl4[(kq * 4 + 1) * 8 + l8];
        float4 w2 = Wl4[(kq * 4 + 2) * 8 + l8];
        float4 w3 = Wl4[(kq * 4 + 3) * 8 + l8];
#pragma unroll
        for (int i = 0; i < 4; i++) {
            float4 hv = H4[(r0 + i) * 35 + kq];
            acc[i][0] += hv.x * w0.x; acc[i][1] += hv.x * w0.y;
            acc[i][2] += hv.x * w0.z; acc[i][3] += hv.x * w0.w;
            acc[i][0] += hv.y * w1.x; acc[i][1] += hv.y * w1.y;
            acc[i][2] += hv.y * w1.z; acc[i][3] += hv.y * w1.w;
            acc[i][0] += hv.z * w2.x; acc[i][1] += hv.z * w2.y;
            acc[i][2] += hv.z * w2.z; acc[i][3] += hv.z * w2.w;
            acc[i][0] += hv.w * w3.x; acc[i][1] += hv.w * w3.y;
            acc[i][2] += hv.w * w3.z; acc[i][3] += hv.w * w3.w;
        }
    }

    float4 alo = ((const float4*)a)[l8];
    float4 ahi = ((const float4*)a)[8 + l8];
#pragma unroll
    for (int i = 0; i < 4; i++) {
        int row = rowBase + r0 + i;
        if (row < N) {
            float4 zv = make_float4(acc[i][0], acc[i][1], acc[i][2], acc[i][3]);
            *(float4*)&z[(size_t)row * 32 + col4] = zv;
            float ps = zv.x * alo.x + zv.y * alo.y + zv.z * alo.z + zv.w * alo.w;
            float pd = zv.x * ahi.x + zv.y * ahi.y + zv.z * ahi.z + zv.w * ahi.w;
            ps += __shfl_xor(ps, 1, 64); ps += __shfl_xor(ps, 2, 64); ps += __shfl_xor(ps, 4, 64);
            pd += __shfl_xor(pd, 1, 64); pd += __shfl_xor(pd, 2, 64); pd += __shfl_xor(pd, 4, 64);
            if (l8 == 0) { s_src[row] = ps; s_dst[row] = pd; }
        }
    }
}

__global__ __launch_bounds__(128) void gemm2_kernel(
    const float* __restrict__ h, const float* __restrict__ W,
    const float* __restrict__ a, float* __restrict__ z,
    float* __restrict__ s_src, float* __restrict__ s_dst, int N)
{
    __shared__ float Hl[64 * 44];
    __shared__ float Wl[32 * 32];
    int tid = threadIdx.x;
    int rowBase = blockIdx.x * 64;

    {
        const float4* W4 = (const float4*)W;
        float4* Wl4 = (float4*)Wl;
        for (int i = tid; i < 256; i += 128) Wl4[i] = W4[i];
    }
    {
        const float4* h4 = (const float4*)h;
        for (int i = tid; i < 64 * 8; i += 128) {
            int r = i >> 3, kq = i & 7;
            float4 v = (rowBase + r < N) ? h4[(size_t)(rowBase + r) * 8 + kq]
                                         : make_float4(0.f, 0.f, 0.f, 0.f);
            *(float4*)&Hl[r * 44 + kq * 4] = v;
        }
    }
    __syncthreads();

    int wv   = tid >> 6;
    int lane = tid & 63;
    int g    = lane >> 3;
    int l8   = lane & 7;
    int r0   = wv * 32 + g * 4;
    int col4 = l8 * 4;

    float acc[4][4];
#pragma unroll
    for (int i = 0; i < 4; i++)
#pragma unroll
        for (int c = 0; c < 4; c++) acc[i][c] = 0.f;

    const float4* H4  = (const float4*)Hl;
    const float4* Wl4 = (const float4*)Wl;

#pragma unroll
    for (int kq = 0; kq < 8; kq++) {
        float4 w0 = Wl4[(kq * 4 + 0) * 8 + l8];
        float4 w1 = Wl4[(kq * 4 + 1) * 8 + l8];
        float4 w2 = Wl4[(kq * 4 + 2) * 8 + l8];
        float4 w3 = Wl4[(kq * 4 + 3) * 8 + l8];
#pragma unroll
        for (int i = 0; i < 4; i++) {
            float4 hv = H4[(r0 + i) * 11 + kq];
            acc[i][0] += hv.x * w0.x; acc[i][1] += hv.x * w0.y;
            acc[i][2] += hv.x * w0.z; acc[i][3] += hv.x * w0.w;
            acc[i][0] += hv.y * w1.x; acc[i][1] += hv.y * w1.y;
            acc[i][2] += hv.y * w1.z; acc[i][3] += hv.y * w1.w;
            acc[i][0] += hv.z * w2.x; acc[i][1] += hv.z * w2.y;
            acc[i][2] += hv.z * w2.z; acc[i][3] += hv.z * w2.w;
            acc[i][0] += hv.w * w3.x; acc[i][1] += hv.w * w3.y;
            acc[i][2] += hv.w * w3.z; acc[i][3] += hv.w * w3.w;
        }
    }

    float4 alo = ((const float4*)a)[l8];
    float4 ahi = ((const float4*)a)[8 + l8];
#pragma unroll
    for (int i = 0; i < 4; i++) {
        int row = rowBase + r0 + i;
        if (row < N) {
            float4 zv = make_float4(acc[i][0], acc[i][1], acc[i][2], acc[i][3]);
            *(float4*)&z[(size_t)row * 32 + col4] = zv;
            float ps = zv.x * alo.x + zv.y * alo.y + zv.z * alo.z + zv.w * alo.w;
            float pd = zv.x * ahi.x + zv.y * ahi.y + zv.z * ahi.z + zv.w * ahi.w;
            ps += __shfl_xor(ps, 1, 64); ps += __shfl_xor(ps, 2, 64); ps += __shfl_xor(ps, 4, 64);
            pd += __shfl_xor(pd, 1, 64); pd += __shfl_xor(pd, 2, 64); pd += __shfl_xor(pd, 4, 64);
            if (l8 == 0) { s_src[row] = ps; s_dst[row] = pd; }
        }
    }
}

// layer 3: zs[i] = {z, z*a0} interleaved (single-line gather in agg1), s_dst sep.
__global__ __launch_bounds__(256) void gemm3_kernel(
    const float* __restrict__ h, const float* __restrict__ W,
    const float* __restrict__ a, float2* __restrict__ zs,
    float* __restrict__ s_dst, int N)
{
    int i = blockIdx.x * 256 + threadIdx.x;
    if (i >= N) return;
    const float4* hp = (const float4*)(h + (size_t)i * 32);
    const float4* wp = (const float4*)W;
    float acc = 0.f;
#pragma unroll
    for (int c = 0; c < 8; c++) {
        float4 v = hp[c];
        float4 w = wp[c];
        acc += v.x * w.x + v.y * w.y + v.z * w.z + v.w * w.w;
    }
    zs[i] = make_float2(acc, acc * a[0]);
    s_dst[i] = acc * a[1];
}

// ============================================================================
// Atomic-free CSR build: two-level counting sort by dst (LDS atomics only).
// Bucket = dst >> 8 (256 nodes/bucket). Tiles of 4096 edges.
// ============================================================================

#define TILE_E 4096
#define NB_MAX 512     // supports N <= 131072

__global__ __launch_bounds__(256) void csr_hist_kernel(
    const int* __restrict__ dst, int* __restrict__ counts,
    int E, int TB, int NB)
{
    __shared__ int hist[NB_MAX];
    int tid = threadIdx.x;
    int t = blockIdx.x;
    for (int b = tid; b < NB; b += 256) hist[b] = 0;
    __syncthreads();
    int base = t * TILE_E;
    for (int i = tid; i < TILE_E; i += 256) {
        int k = base + i;
        if (k < E) atomicAdd(&hist[dst[k] >> 8], 1);
    }
    __syncthreads();
    for (int b = tid; b < NB; b += 256) counts[b * TB + t] = hist[b];
}

__global__ __launch_bounds__(256) void scan1_kernel(
    const int* __restrict__ vals, int* __restrict__ incl,
    int* __restrict__ blockSums, int M)
{
    __shared__ int tmp[256];
    int tid = threadIdx.x;
    int i = blockIdx.x * 256 + tid;
    int v = (i < M) ? vals[i] : 0;
    tmp[tid] = v;
    __syncthreads();
#pragma unroll
    for (int off = 1; off < 256; off <<= 1) {
        int t = (tid >= off) ? tmp[tid - off] : 0;
        __syncthreads();
        tmp[tid] += t;
        __syncthreads();
    }
    if (i < M) incl[i] = tmp[tid];
    if (tid == 255) blockSums[blockIdx.x] = tmp[255];
}

__global__ __launch_bounds__(1024) void scan2_kernel(int* __restrict__ blockSums, int nb)
{
    __shared__ int tmp[1024];
    int tid = threadIdx.x;
    int v = (tid < nb) ? blockSums[tid] : 0;
    tmp[tid] = v;
    __syncthreads();
#pragma unroll
    for (int off = 1; off < 1024; off <<= 1) {
        int t = (tid >= off) ? tmp[tid - off] : 0;
        __syncthreads();
        tmp[tid] += t;
        __syncthreads();
    }
    if (tid < nb) blockSums[tid] = tmp[tid] - v;  // exclusive
}

__global__ __launch_bounds__(256) void scan3_kernel(
    const int* __restrict__ vals, const int* __restrict__ blockSums,
    int* __restrict__ cscan, int M, int E)
{
    int i = blockIdx.x * 256 + threadIdx.x;
    if (i < M) {
        cscan[i] = cscan[i] - vals[i] + blockSums[i >> 8];
    }
    if (i == 0) cscan[M] = E;
}

__global__ __launch_bounds__(256) void csr_scatter_kernel(
    const int* __restrict__ src, const int* __restrict__ dst,
    const int* __restrict__ cscan, int2* __restrict__ ebuf,
    int E, int TB, int NB)
{
    __shared__ int baseB[NB_MAX];
    __shared__ int cur[NB_MAX];
    int tid = threadIdx.x;
    int t = blockIdx.x;
    for (int b = tid; b < NB; b += 256) {
        baseB[b] = cscan[b * TB + t];
        cur[b] = 0;
    }
    __syncthreads();
    int base = t * TILE_E;
    for (int i = tid; i < TILE_E; i += 256) {
        int k = base + i;
        if (k < E) {
            int d = dst[k], s = src[k];
            int b = d >> 8;
            int r = atomicAdd(&cur[b], 1);
            ebuf[baseB[b] + r] = make_int2(s, d & 255);
        }
    }
}

__global__ __launch_bounds__(256) void csr_bucket_kernel(
    const int2* __restrict__ ebuf, const int* __restrict__ cscan,
    int* __restrict__ csr_src, int* __restrict__ offsets,
    int N, int E, int TB)
{
    __shared__ int2 eb[6144];     // 48KB staging
    __shared__ int hist[256];
    __shared__ int loff[256];
    __shared__ int tmp[256];
    int tid = threadIdx.x;
    int b = blockIdx.x;

    int beg = cscan[b * TB];
    int endv = cscan[(b + 1) * TB];
    int cnt = endv - beg;
    int first = b << 8;

    hist[tid] = 0;
    __syncthreads();

    bool inLds = (cnt <= 6144);
    for (int i = tid; i < cnt; i += 256) {
        int2 v = ebuf[beg + i];
        if (inLds) eb[i] = v;
        atomicAdd(&hist[v.y], 1);
    }
    __syncthreads();

    int hv = hist[tid];
    tmp[tid] = hv;
    __syncthreads();
#pragma unroll
    for (int off = 1; off < 256; off <<= 1) {
        int t = (tid >= off) ? tmp[tid - off] : 0;
        __syncthreads();
        tmp[tid] += t;
        __syncthreads();
    }
    loff[tid] = tmp[tid] - hv;
    __syncthreads();

    if (first + tid < N) offsets[first + tid] = beg + loff[tid];
    if (b == 0 && tid == 0) offsets[N] = E;

    hist[tid] = 0;
    __syncthreads();

    for (int i = tid; i < cnt; i += 256) {
        int2 v = inLds ? eb[i] : ebuf[beg + i];
        int r = atomicAdd(&hist[v.y], 1);
        csr_src[beg + loff[v.y] + r] = v.x;
    }
}

// ============================================================================
// Fused softmax + aggregation. 32-lane group per node.
// Phase A: edge-parallel logits, shuffle-reduce max/denom; spill (w,s) pairs
// to per-group LDS. Phase B: branch-free 4x-unrolled gather loop — 4
// independent z-row loads in flight per group (R8 fix: the shfl-broadcast
// loop was a serialized shfl->load->fma chain at ~500 cyc/edge).
// ============================================================================

__global__ __launch_bounds__(256) void agg32_fused_kernel(
    const int* __restrict__ offsets, const int* __restrict__ csr_src,
    const float* __restrict__ s_src, const float* __restrict__ s_dst,
    const float* __restrict__ z, float* __restrict__ h, int N)
{
    __shared__ float2 wsbuf[8 * 128];   // 8 groups x 128 edges x {w, s}
    int g    = threadIdx.x >> 5;
    int lane = threadIdx.x & 31;
    int node = blockIdx.x * 8 + g;
    if (node >= N) return;
    float2* ws = &wsbuf[g * 128];

    int beg = offsets[node], end = offsets[node + 1];
    int deg = end - beg;
    float sd = s_dst[node];
    float o = 0.f;
    float rden;

    if (deg <= 128) {
        int   sreg[4];
        float ev[4];
        int nIter = (deg + 31) >> 5;
        float m = -3.0e38f;
#pragma unroll 4
        for (int it = 0; it < nIter; ++it) {
            int p = beg + it * 32 + lane;
            float e = -3.0e38f;
            int s = 0;
            if (p < end) {
                s = csr_src[p];
                e = s_src[s] + sd;
                e = (e > 0.f) ? e : NEG_SLOPE * e;
            }
            sreg[it] = s;
            ev[it] = e;
            m = fmaxf(m, e);
        }
#pragma unroll
        for (int off = 16; off > 0; off >>= 1) m = fmaxf(m, __shfl_xor(m, off, 32));

        float l = 0.f;
#pragma unroll 4
        for (int it = 0; it < nIter; ++it) {
            int p = beg + it * 32 + lane;
            float w = (p < end) ? __expf(ev[it] - m) : 0.f;
            ws[it * 32 + lane] = make_float2(w, __int_as_float(sreg[it]));
            l += w;
        }
#pragma unroll
        for (int off = 16; off > 0; off >>= 1) l += __shfl_xor(l, off, 32);
        rden = 1.f / fmaxf(l, 1e-9f);

        // phase B: branch-free, 4 independent gathers in flight
        int p = 0;
        for (; p + 4 <= deg; p += 4) {
            float2 a0 = ws[p],     a1 = ws[p + 1];
            float2 a2 = ws[p + 2], a3 = ws[p + 3];
            int s0 = __float_as_int(a0.y), s1 = __float_as_int(a1.y);
            int s2 = __float_as_int(a2.y), s3 = __float_as_int(a3.y);
            float z0 = z[(size_t)s0 * 32 + lane];
            float z1 = z[(size_t)s1 * 32 + lane];
            float z2 = z[(size_t)s2 * 32 + lane];
            float z3 = z[(size_t)s3 * 32 + lane];
            o += a0.x * z0;
            o += a1.x * z1;
            o += a2.x * z2;
            o += a3.x * z3;
        }
        for (; p < deg; ++p) {
            float2 aa = ws[p];
            o += aa.x * z[(size_t)__float_as_int(aa.y) * 32 + lane];
        }
    } else {
        // rare fallback (deg > 128): streaming recompute
        float m = -3.0e38f;
        for (int p = beg + lane; p < end; p += 32) {
            float e = s_src[csr_src[p]] + sd;
            e = (e > 0.f) ? e : NEG_SLOPE * e;
            m = fmaxf(m, e);
        }
#pragma unroll
        for (int off = 16; off > 0; off >>= 1) m = fmaxf(m, __shfl_xor(m, off, 32));
        float l = 0.f;
        for (int p = beg + lane; p < end; p += 32) {
            float e = s_src[csr_src[p]] + sd;
            e = (e > 0.f) ? e : NEG_SLOPE * e;
            l += __expf(e - m);
        }
#pragma unroll
        for (int off = 16; off > 0; off >>= 1) l += __shfl_xor(l, off, 32);
        rden = 1.f / fmaxf(l, 1e-9f);
        for (int p = beg; p < end; ++p) {
            int s = csr_src[p];                    // uniform
            float e = s_src[s] + sd;
            e = (e > 0.f) ? e : NEG_SLOPE * e;
            float w = __expf(e - m);
            o += w * z[(size_t)s * 32 + lane];
        }
    }

    float v = o * rden;
    h[(size_t)node * 32 + lane] = (v > 0.f) ? v : 0.f;  // relu
}

// d_out = 1: fully edge-parallel, one 8B gather per edge, fused sigmoid
__global__ __launch_bounds__(256) void agg1_fused_kernel(
    const int* __restrict__ offsets, const int* __restrict__ csr_src,
    const float2* __restrict__ zs, const float* __restrict__ s_dst,
    float* __restrict__ out, int N)
{
    int node = blockIdx.x * 8 + (threadIdx.x >> 5);
    int lane = threadIdx.x & 31;
    if (node >= N) return;

    int beg = offsets[node], end = offsets[node + 1];
    int deg = end - beg;
    float sd = s_dst[node];

    if (deg <= 128) {
        float ev[4], zv[4];
        int nIter = (deg + 31) >> 5;
        float m = -3.0e38f;
#pragma unroll 4
        for (int it = 0; it < nIter; ++it) {
            int p = beg + it * 32 + lane;
            float e = -3.0e38f, zz = 0.f;
            if (p < end) {
                float2 v2 = zs[csr_src[p]];
                zz = v2.x;
                e = v2.y + sd;
                e = (e > 0.f) ? e : NEG_SLOPE * e;
            }
            ev[it] = e; zv[it] = zz;
            m = fmaxf(m, e);
        }
#pragma unroll
        for (int off = 16; off > 0; off >>= 1) m = fmaxf(m, __shfl_xor(m, off, 32));
        float l = 0.f, o = 0.f;
#pragma unroll 4
        for (int it = 0; it < nIter; ++it) {
            int p = beg + it * 32 + lane;
            float w = (p < end) ? __expf(ev[it] - m) : 0.f;
            l += w;
            o += w * zv[it];
        }
#pragma unroll
        for (int off = 16; off > 0; off >>= 1) {
            l += __shfl_xor(l, off, 32);
            o += __shfl_xor(o, off, 32);
        }
        if (lane == 0) {
            float v = o / fmaxf(l, 1e-9f);
            out[node] = 1.f / (1.f + __expf(-v));
        }
    } else {
        float m = -3.0e38f;
        for (int p = beg + lane; p < end; p += 32) {
            float e = zs[csr_src[p]].y + sd;
            e = (e > 0.f) ? e : NEG_SLOPE * e;
            m = fmaxf(m, e);
        }
#pragma unroll
        for (int off = 16; off > 0; off >>= 1) m = fmaxf(m, __shfl_xor(m, off, 32));
        float l = 0.f, o = 0.f;
        for (int p = beg + lane; p < end; p += 32) {
            float2 v2 = zs[csr_src[p]];
            float e = v2.y + sd;
            e = (e > 0.f) ? e : NEG_SLOPE * e;
            float w = __expf(e - m);
            l += w; o += w * v2.x;
        }
#pragma unroll
        for (int off = 16; off > 0; off >>= 1) {
            l += __shfl_xor(l, off, 32);
            o += __shfl_xor(o, off, 32);
        }
        if (lane == 0) {
            float v = o / fmaxf(l, 1e-9f);
            out[node] = 1.f / (1.f + __expf(-v));
        }
    }
}

// ============================================================================

extern "C" void kernel_launch(void* const* d_in, const int* in_sizes, int n_in,
                              void* d_out, int out_size, void* d_ws, size_t ws_size,
                              hipStream_t stream)
{
    const float* feature = (const float*)d_in[0];
    const int*   src     = (const int*)d_in[1];
    const int*   dst     = (const int*)d_in[2];
    const float* W1      = (const float*)d_in[3];
    const float* a1      = (const float*)d_in[4];
    const float* W2      = (const float*)d_in[5];
    const float* a2      = (const float*)d_in[6];
    const float* W3      = (const float*)d_in[7];
    const float* a3      = (const float*)d_in[8];
    float* out = (float*)d_out;

    const int N = in_sizes[0] / 128;
    const int E = in_sizes[1];

    const int TB = (E + TILE_E - 1) / TILE_E;     // edge tiles
    const int NB = (N + 255) >> 8;                // buckets
    const int M  = NB * TB;

    // ---- workspace layout ----
    char* p = (char*)d_ws;
    float* zbuf    = (float*)p;  p += (size_t)N * 32 * sizeof(float);
    float* hbuf    = (float*)p;  p += (size_t)N * 32 * sizeof(float);
    float* s_src   = (float*)p;  p += (size_t)N * sizeof(float);
    float* s_dst   = (float*)p;  p += (size_t)N * sizeof(float);
    int*   offsets = (int*)p;    p += ((size_t)N + 1) * sizeof(int);
    int*   counts  = (int*)p;    p += ((size_t)M + 1) * sizeof(int);
    int*   cscan   = (int*)p;    p += ((size_t)M + 1) * sizeof(int);
    int*   blockSums = (int*)p;  p += 1024 * sizeof(int);
    int2*  ebuf    = (int2*)p;   p += (size_t)E * sizeof(int2);
    int*   csr_src = (int*)p;    p += (size_t)E * sizeof(int);

    const int nodeBlocks8  = (N + 7) / 8;
    const int nodeBlocks   = (N + 255) / 256;
    const int gemmBlocks64 = (N + 63) / 64;
    const int scanBlocksM  = (M + 255) / 256;

    // ---- build CSR: atomic-free two-level counting sort ----
    hipLaunchKernelGGL(csr_hist_kernel, dim3(TB), dim3(256), 0, stream,
                       dst, counts, E, TB, NB);
    hipLaunchKernelGGL(scan1_kernel, dim3(scanBlocksM), dim3(256), 0, stream,
                       counts, cscan, blockSums, M);
    hipLaunchKernelGGL(scan2_kernel, dim3(1), dim3(1024), 0, stream,
                       blockSums, scanBlocksM);
    hipLaunchKernelGGL(scan3_kernel, dim3(scanBlocksM), dim3(256), 0, stream,
                       counts, blockSums, cscan, M, E);
    hipLaunchKernelGGL(csr_scatter_kernel, dim3(TB), dim3(256), 0, stream,
                       src, dst, cscan, ebuf, E, TB, NB);
    hipLaunchKernelGGL(csr_bucket_kernel, dim3(NB), dim3(256), 0, stream,
                       ebuf, cscan, csr_src, offsets, N, E, TB);

    // ---- layer 1 (128 -> 32, relu) ----
    hipLaunchKernelGGL(gemm1_kernel, dim3(gemmBlocks64), dim3(128), 0, stream,
                       feature, W1, a1, zbuf, s_src, s_dst, N);
    hipLaunchKernelGGL(agg32_fused_kernel, dim3(nodeBlocks8), dim3(256), 0, stream,
                       offsets, csr_src, s_src, s_dst, zbuf, hbuf, N);

    // ---- layer 2 (32 -> 32, relu) ----
    hipLaunchKernelGGL(gemm2_kernel, dim3(gemmBlocks64), dim3(128), 0, stream,
                       hbuf, W2, a2, zbuf, s_src, s_dst, N);
    hipLaunchKernelGGL(agg32_fused_kernel, dim3(nodeBlocks8), dim3(256), 0, stream,
                       offsets, csr_src, s_src, s_dst, zbuf, hbuf, N);

    // ---- layer 3 (32 -> 1, sigmoid) ----
    float2* zs = (float2*)zbuf;
    hipLaunchKernelGGL(gemm3_kernel, dim3(nodeBlocks), dim3(256), 0, stream,
                       hbuf, W3, a3, zs, s_dst, N);
    hipLaunchKernelGGL(agg1_fused_kernel, dim3(nodeBlocks8), dim3(256), 0, stream,
                       offsets, csr_src, zs, s_dst, out, N);
}

// Round 10
// 280.665 us; speedup vs baseline: 1.7724x; 1.0625x over previous
//
#include <hip/hip_runtime.h>
#include <cstdint>
#include <cstddef>

#define NEG_SLOPE 0.01f

// ============================================================================
// GEMM kernels — register-blocked 4x4 micro-tiles
// ============================================================================

// z = h[N,128] @ W[128,32] + logits. 128 threads, 64 rows/block.
// R9 fix: h is read DIRECTLY from global (same-address broadcast across the
// 8-lane col-group, 64B line reused over 4 consecutive kq) instead of a 36KB
// LDS stage — LDS 52->16KB lifts occupancy 3 blocks/CU -> 10 blocks/CU.
__global__ __launch_bounds__(128) void gemm1_kernel(
    const float* __restrict__ h, const float* __restrict__ W,
    const float* __restrict__ a, float* __restrict__ z,
    float* __restrict__ s_src, float* __restrict__ s_dst, int N)
{
    __shared__ float Wl[128 * 32];   // 16384 B only
    int tid = threadIdx.x;
    int rowBase = blockIdx.x * 64;

    {
        const float4* W4 = (const float4*)W;
        float4* Wl4 = (float4*)Wl;
        for (int i = tid; i < 1024; i += 128) Wl4[i] = W4[i];
    }
    __syncthreads();

    int wv   = tid >> 6;
    int lane = tid & 63;
    int g    = lane >> 3;
    int l8   = lane & 7;
    int r0   = wv * 32 + g * 4;
    int col4 = l8 * 4;

    float acc[4][4];
#pragma unroll
    for (int i = 0; i < 4; i++)
#pragma unroll
        for (int c = 0; c < 4; c++) acc[i][c] = 0.f;

    const float4* h4  = (const float4*)h;     // row stride 32 float4
    const float4* Wl4 = (const float4*)Wl;

    // clamp rows (epilogue guard discards the duplicates)
    size_t rowOff[4];
#pragma unroll
    for (int i = 0; i < 4; i++) {
        int r = rowBase + r0 + i;
        rowOff[i] = (size_t)((r < N) ? r : (N - 1)) * 32;
    }

#pragma unroll 2
    for (int kq = 0; kq < 32; kq++) {
        float4 w0 = Wl4[(kq * 4 + 0) * 8 + l8];
        float4 w1 = Wl4[(kq * 4 + 1) * 8 + l8];
        float4 w2 = Wl4[(kq * 4 + 2) * 8 + l8];
        float4 w3 = Wl4[(kq * 4 + 3) * 8 + l8];
#pragma unroll
        for (int i = 0; i < 4; i++) {
            float4 hv = h4[rowOff[i] + kq];   // global, broadcast across l8
            acc[i][0] += hv.x * w0.x; acc[i][1] += hv.x * w0.y;
            acc[i][2] += hv.x * w0.z; acc[i][3] += hv.x * w0.w;
            acc[i][0] += hv.y * w1.x; acc[i][1] += hv.y * w1.y;
            acc[i][2] += hv.y * w1.z; acc[i][3] += hv.y * w1.w;
            acc[i][0] += hv.z * w2.x; acc[i][1] += hv.z * w2.y;
            acc[i][2] += hv.z * w2.z; acc[i][3] += hv.z * w2.w;
            acc[i][0] += hv.w * w3.x; acc[i][1] += hv.w * w3.y;
            acc[i][2] += hv.w * w3.z; acc[i][3] += hv.w * w3.w;
        }
    }

    float4 alo = ((const float4*)a)[l8];
    float4 ahi = ((const float4*)a)[8 + l8];
#pragma unroll
    for (int i = 0; i < 4; i++) {
        int row = rowBase + r0 + i;
        if (row < N) {
            float4 zv = make_float4(acc[i][0], acc[i][1], acc[i][2], acc[i][3]);
            *(float4*)&z[(size_t)row * 32 + col4] = zv;
            float ps = zv.x * alo.x + zv.y * alo.y + zv.z * alo.z + zv.w * alo.w;
            float pd = zv.x * ahi.x + zv.y * ahi.y + zv.z * ahi.z + zv.w * ahi.w;
            ps += __shfl_xor(ps, 1, 64); ps += __shfl_xor(ps, 2, 64); ps += __shfl_xor(ps, 4, 64);
            pd += __shfl_xor(pd, 1, 64); pd += __shfl_xor(pd, 2, 64); pd += __shfl_xor(pd, 4, 64);
            if (l8 == 0) { s_src[row] = ps; s_dst[row] = pd; }
        }
    }
}

__global__ __launch_bounds__(128) void gemm2_kernel(
    const float* __restrict__ h, const float* __restrict__ W,
    const float* __restrict__ a, float* __restrict__ z,
    float* __restrict__ s_src, float* __restrict__ s_dst, int N)
{
    __shared__ float Hl[64 * 44];
    __shared__ float Wl[32 * 32];
    int tid = threadIdx.x;
    int rowBase = blockIdx.x * 64;

    {
        const float4* W4 = (const float4*)W;
        float4* Wl4 = (float4*)Wl;
        for (int i = tid; i < 256; i += 128) Wl4[i] = W4[i];
    }
    {
        const float4* h4 = (const float4*)h;
        for (int i = tid; i < 64 * 8; i += 128) {
            int r = i >> 3, kq = i & 7;
            float4 v = (rowBase + r < N) ? h4[(size_t)(rowBase + r) * 8 + kq]
                                         : make_float4(0.f, 0.f, 0.f, 0.f);
            *(float4*)&Hl[r * 44 + kq * 4] = v;
        }
    }
    __syncthreads();

    int wv   = tid >> 6;
    int lane = tid & 63;
    int g    = lane >> 3;
    int l8   = lane & 7;
    int r0   = wv * 32 + g * 4;
    int col4 = l8 * 4;

    float acc[4][4];
#pragma unroll
    for (int i = 0; i < 4; i++)
#pragma unroll
        for (int c = 0; c < 4; c++) acc[i][c] = 0.f;

    const float4* H4  = (const float4*)Hl;
    const float4* Wl4 = (const float4*)Wl;

#pragma unroll
    for (int kq = 0; kq < 8; kq++) {
        float4 w0 = Wl4[(kq * 4 + 0) * 8 + l8];
        float4 w1 = Wl4[(kq * 4 + 1) * 8 + l8];
        float4 w2 = Wl4[(kq * 4 + 2) * 8 + l8];
        float4 w3 = Wl4[(kq * 4 + 3) * 8 + l8];
#pragma unroll
        for (int i = 0; i < 4; i++) {
            float4 hv = H4[(r0 + i) * 11 + kq];
            acc[i][0] += hv.x * w0.x; acc[i][1] += hv.x * w0.y;
            acc[i][2] += hv.x * w0.z; acc[i][3] += hv.x * w0.w;
            acc[i][0] += hv.y * w1.x; acc[i][1] += hv.y * w1.y;
            acc[i][2] += hv.y * w1.z; acc[i][3] += hv.y * w1.w;
            acc[i][0] += hv.z * w2.x; acc[i][1] += hv.z * w2.y;
            acc[i][2] += hv.z * w2.z; acc[i][3] += hv.z * w2.w;
            acc[i][0] += hv.w * w3.x; acc[i][1] += hv.w * w3.y;
            acc[i][2] += hv.w * w3.z; acc[i][3] += hv.w * w3.w;
        }
    }

    float4 alo = ((const float4*)a)[l8];
    float4 ahi = ((const float4*)a)[8 + l8];
#pragma unroll
    for (int i = 0; i < 4; i++) {
        int row = rowBase + r0 + i;
        if (row < N) {
            float4 zv = make_float4(acc[i][0], acc[i][1], acc[i][2], acc[i][3]);
            *(float4*)&z[(size_t)row * 32 + col4] = zv;
            float ps = zv.x * alo.x + zv.y * alo.y + zv.z * alo.z + zv.w * alo.w;
            float pd = zv.x * ahi.x + zv.y * ahi.y + zv.z * ahi.z + zv.w * ahi.w;
            ps += __shfl_xor(ps, 1, 64); ps += __shfl_xor(ps, 2, 64); ps += __shfl_xor(ps, 4, 64);
            pd += __shfl_xor(pd, 1, 64); pd += __shfl_xor(pd, 2, 64); pd += __shfl_xor(pd, 4, 64);
            if (l8 == 0) { s_src[row] = ps; s_dst[row] = pd; }
        }
    }
}

// layer 3: zs[i] = {z, z*a0} interleaved (single-line gather in agg1), s_dst sep.
__global__ __launch_bounds__(256) void gemm3_kernel(
    const float* __restrict__ h, const float* __restrict__ W,
    const float* __restrict__ a, float2* __restrict__ zs,
    float* __restrict__ s_dst, int N)
{
    int i = blockIdx.x * 256 + threadIdx.x;
    if (i >= N) return;
    const float4* hp = (const float4*)(h + (size_t)i * 32);
    const float4* wp = (const float4*)W;
    float acc = 0.f;
#pragma unroll
    for (int c = 0; c < 8; c++) {
        float4 v = hp[c];
        float4 w = wp[c];
        acc += v.x * w.x + v.y * w.y + v.z * w.z + v.w * w.w;
    }
    zs[i] = make_float2(acc, acc * a[0]);
    s_dst[i] = acc * a[1];
}

// ============================================================================
// Atomic-free CSR build: two-level counting sort by dst (LDS atomics only).
// ============================================================================

#define TILE_E 4096
#define NB_MAX 512     // supports N <= 131072

__global__ __launch_bounds__(256) void csr_hist_kernel(
    const int* __restrict__ dst, int* __restrict__ counts,
    int E, int TB, int NB)
{
    __shared__ int hist[NB_MAX];
    int tid = threadIdx.x;
    int t = blockIdx.x;
    for (int b = tid; b < NB; b += 256) hist[b] = 0;
    __syncthreads();
    int base = t * TILE_E;
    for (int i = tid; i < TILE_E; i += 256) {
        int k = base + i;
        if (k < E) atomicAdd(&hist[dst[k] >> 8], 1);
    }
    __syncthreads();
    for (int b = tid; b < NB; b += 256) counts[b * TB + t] = hist[b];
}

__global__ __launch_bounds__(256) void scan1_kernel(
    const int* __restrict__ vals, int* __restrict__ incl,
    int* __restrict__ blockSums, int M)
{
    __shared__ int tmp[256];
    int tid = threadIdx.x;
    int i = blockIdx.x * 256 + tid;
    int v = (i < M) ? vals[i] : 0;
    tmp[tid] = v;
    __syncthreads();
#pragma unroll
    for (int off = 1; off < 256; off <<= 1) {
        int t = (tid >= off) ? tmp[tid - off] : 0;
        __syncthreads();
        tmp[tid] += t;
        __syncthreads();
    }
    if (i < M) incl[i] = tmp[tid];
    if (tid == 255) blockSums[blockIdx.x] = tmp[255];
}

__global__ __launch_bounds__(1024) void scan2_kernel(int* __restrict__ blockSums, int nb)
{
    __shared__ int tmp[1024];
    int tid = threadIdx.x;
    int v = (tid < nb) ? blockSums[tid] : 0;
    tmp[tid] = v;
    __syncthreads();
#pragma unroll
    for (int off = 1; off < 1024; off <<= 1) {
        int t = (tid >= off) ? tmp[tid - off] : 0;
        __syncthreads();
        tmp[tid] += t;
        __syncthreads();
    }
    if (tid < nb) blockSums[tid] = tmp[tid] - v;  // exclusive
}

__global__ __launch_bounds__(256) void scan3_kernel(
    const int* __restrict__ vals, const int* __restrict__ blockSums,
    int* __restrict__ cscan, int M, int E)
{
    int i = blockIdx.x * 256 + threadIdx.x;
    if (i < M) {
        cscan[i] = cscan[i] - vals[i] + blockSums[i >> 8];
    }
    if (i == 0) cscan[M] = E;
}

__global__ __launch_bounds__(256) void csr_scatter_kernel(
    const int* __restrict__ src, const int* __restrict__ dst,
    const int* __restrict__ cscan, int2* __restrict__ ebuf,
    int E, int TB, int NB)
{
    __shared__ int baseB[NB_MAX];
    __shared__ int cur[NB_MAX];
    int tid = threadIdx.x;
    int t = blockIdx.x;
    for (int b = tid; b < NB; b += 256) {
        baseB[b] = cscan[b * TB + t];
        cur[b] = 0;
    }
    __syncthreads();
    int base = t * TILE_E;
    for (int i = tid; i < TILE_E; i += 256) {
        int k = base + i;
        if (k < E) {
            int d = dst[k], s = src[k];
            int b = d >> 8;
            int r = atomicAdd(&cur[b], 1);
            ebuf[baseB[b] + r] = make_int2(s, d & 255);
        }
    }
}

__global__ __launch_bounds__(256) void csr_bucket_kernel(
    const int2* __restrict__ ebuf, const int* __restrict__ cscan,
    int* __restrict__ csr_src, int* __restrict__ offsets,
    int N, int E, int TB)
{
    __shared__ int2 eb[6144];     // 48KB staging
    __shared__ int hist[256];
    __shared__ int loff[256];
    __shared__ int tmp[256];
    int tid = threadIdx.x;
    int b = blockIdx.x;

    int beg = cscan[b * TB];
    int endv = cscan[(b + 1) * TB];
    int cnt = endv - beg;
    int first = b << 8;

    hist[tid] = 0;
    __syncthreads();

    bool inLds = (cnt <= 6144);
    for (int i = tid; i < cnt; i += 256) {
        int2 v = ebuf[beg + i];
        if (inLds) eb[i] = v;
        atomicAdd(&hist[v.y], 1);
    }
    __syncthreads();

    int hv = hist[tid];
    tmp[tid] = hv;
    __syncthreads();
#pragma unroll
    for (int off = 1; off < 256; off <<= 1) {
        int t = (tid >= off) ? tmp[tid - off] : 0;
        __syncthreads();
        tmp[tid] += t;
        __syncthreads();
    }
    loff[tid] = tmp[tid] - hv;
    __syncthreads();

    if (first + tid < N) offsets[first + tid] = beg + loff[tid];
    if (b == 0 && tid == 0) offsets[N] = E;

    hist[tid] = 0;
    __syncthreads();

    for (int i = tid; i < cnt; i += 256) {
        int2 v = inLds ? eb[i] : ebuf[beg + i];
        int r = atomicAdd(&hist[v.y], 1);
        csr_src[beg + loff[v.y] + r] = v.x;
    }
}

// ============================================================================
// Fused softmax + aggregation. 32-lane group per node.
// ============================================================================

__global__ __launch_bounds__(256) void agg32_fused_kernel(
    const int* __restrict__ offsets, const int* __restrict__ csr_src,
    const float* __restrict__ s_src, const float* __restrict__ s_dst,
    const float* __restrict__ z, float* __restrict__ h, int N)
{
    __shared__ float2 wsbuf[8 * 128];   // 8 groups x 128 edges x {w, s}
    int g    = threadIdx.x >> 5;
    int lane = threadIdx.x & 31;
    int node = blockIdx.x * 8 + g;
    if (node >= N) return;
    float2* ws = &wsbuf[g * 128];

    int beg = offsets[node], end = offsets[node + 1];
    int deg = end - beg;
    float sd = s_dst[node];
    float o = 0.f;
    float rden;

    if (deg <= 128) {
        int   sreg[4];
        float ev[4];
        int nIter = (deg + 31) >> 5;
        float m = -3.0e38f;
#pragma unroll 4
        for (int it = 0; it < nIter; ++it) {
            int p = beg + it * 32 + lane;
            float e = -3.0e38f;
            int s = 0;
            if (p < end) {
                s = csr_src[p];
                e = s_src[s] + sd;
                e = (e > 0.f) ? e : NEG_SLOPE * e;
            }
            sreg[it] = s;
            ev[it] = e;
            m = fmaxf(m, e);
        }
#pragma unroll
        for (int off = 16; off > 0; off >>= 1) m = fmaxf(m, __shfl_xor(m, off, 32));

        float l = 0.f;
#pragma unroll 4
        for (int it = 0; it < nIter; ++it) {
            int p = beg + it * 32 + lane;
            float w = (p < end) ? __expf(ev[it] - m) : 0.f;
            ws[it * 32 + lane] = make_float2(w, __int_as_float(sreg[it]));
            l += w;
        }
#pragma unroll
        for (int off = 16; off > 0; off >>= 1) l += __shfl_xor(l, off, 32);
        rden = 1.f / fmaxf(l, 1e-9f);

        int p = 0;
        for (; p + 4 <= deg; p += 4) {
            float2 a0 = ws[p],     a1 = ws[p + 1];
            float2 a2 = ws[p + 2], a3 = ws[p + 3];
            int s0 = __float_as_int(a0.y), s1 = __float_as_int(a1.y);
            int s2 = __float_as_int(a2.y), s3 = __float_as_int(a3.y);
            float z0 = z[(size_t)s0 * 32 + lane];
            float z1 = z[(size_t)s1 * 32 + lane];
            float z2 = z[(size_t)s2 * 32 + lane];
            float z3 = z[(size_t)s3 * 32 + lane];
            o += a0.x * z0;
            o += a1.x * z1;
            o += a2.x * z2;
            o += a3.x * z3;
        }
        for (; p < deg; ++p) {
            float2 aa = ws[p];
            o += aa.x * z[(size_t)__float_as_int(aa.y) * 32 + lane];
        }
    } else {
        float m = -3.0e38f;
        for (int p = beg + lane; p < end; p += 32) {
            float e = s_src[csr_src[p]] + sd;
            e = (e > 0.f) ? e : NEG_SLOPE * e;
            m = fmaxf(m, e);
        }
#pragma unroll
        for (int off = 16; off > 0; off >>= 1) m = fmaxf(m, __shfl_xor(m, off, 32));
        float l = 0.f;
        for (int p = beg + lane; p < end; p += 32) {
            float e = s_src[csr_src[p]] + sd;
            e = (e > 0.f) ? e : NEG_SLOPE * e;
            l += __expf(e - m);
        }
#pragma unroll
        for (int off = 16; off > 0; off >>= 1) l += __shfl_xor(l, off, 32);
        rden = 1.f / fmaxf(l, 1e-9f);
        for (int p = beg; p < end; ++p) {
            int s = csr_src[p];                    // uniform
            float e = s_src[s] + sd;
            e = (e > 0.f) ? e : NEG_SLOPE * e;
            float w = __expf(e - m);
            o += w * z[(size_t)s * 32 + lane];
        }
    }

    float v = o * rden;
    h[(size_t)node * 32 + lane] = (v > 0.f) ? v : 0.f;  // relu
}

// d_out = 1: fully edge-parallel, one 8B gather per edge, fused sigmoid
__global__ __launch_bounds__(256) void agg1_fused_kernel(
    const int* __restrict__ offsets, const int* __restrict__ csr_src,
    const float2* __restrict__ zs, const float* __restrict__ s_dst,
    float* __restrict__ out, int N)
{
    int node = blockIdx.x * 8 + (threadIdx.x >> 5);
    int lane = threadIdx.x & 31;
    if (node >= N) return;

    int beg = offsets[node], end = offsets[node + 1];
    int deg = end - beg;
    float sd = s_dst[node];

    if (deg <= 128) {
        float ev[4], zv[4];
        int nIter = (deg + 31) >> 5;
        float m = -3.0e38f;
#pragma unroll 4
        for (int it = 0; it < nIter; ++it) {
            int p = beg + it * 32 + lane;
            float e = -3.0e38f, zz = 0.f;
            if (p < end) {
                float2 v2 = zs[csr_src[p]];
                zz = v2.x;
                e = v2.y + sd;
                e = (e > 0.f) ? e : NEG_SLOPE * e;
            }
            ev[it] = e; zv[it] = zz;
            m = fmaxf(m, e);
        }
#pragma unroll
        for (int off = 16; off > 0; off >>= 1) m = fmaxf(m, __shfl_xor(m, off, 32));
        float l = 0.f, o = 0.f;
#pragma unroll 4
        for (int it = 0; it < nIter; ++it) {
            int p = beg + it * 32 + lane;
            float w = (p < end) ? __expf(ev[it] - m) : 0.f;
            l += w;
            o += w * zv[it];
        }
#pragma unroll
        for (int off = 16; off > 0; off >>= 1) {
            l += __shfl_xor(l, off, 32);
            o += __shfl_xor(o, off, 32);
        }
        if (lane == 0) {
            float v = o / fmaxf(l, 1e-9f);
            out[node] = 1.f / (1.f + __expf(-v));
        }
    } else {
        float m = -3.0e38f;
        for (int p = beg + lane; p < end; p += 32) {
            float e = zs[csr_src[p]].y + sd;
            e = (e > 0.f) ? e : NEG_SLOPE * e;
            m = fmaxf(m, e);
        }
#pragma unroll
        for (int off = 16; off > 0; off >>= 1) m = fmaxf(m, __shfl_xor(m, off, 32));
        float l = 0.f, o = 0.f;
        for (int p = beg + lane; p < end; p += 32) {
            float2 v2 = zs[csr_src[p]];
            float e = v2.y + sd;
            e = (e > 0.f) ? e : NEG_SLOPE * e;
            float w = __expf(e - m);
            l += w; o += w * v2.x;
        }
#pragma unroll
        for (int off = 16; off > 0; off >>= 1) {
            l += __shfl_xor(l, off, 32);
            o += __shfl_xor(o, off, 32);
        }
        if (lane == 0) {
            float v = o / fmaxf(l, 1e-9f);
            out[node] = 1.f / (1.f + __expf(-v));
        }
    }
}

// ============================================================================

extern "C" void kernel_launch(void* const* d_in, const int* in_sizes, int n_in,
                              void* d_out, int out_size, void* d_ws, size_t ws_size,
                              hipStream_t stream)
{
    const float* feature = (const float*)d_in[0];
    const int*   src     = (const int*)d_in[1];
    const int*   dst     = (const int*)d_in[2];
    const float* W1      = (const float*)d_in[3];
    const float* a1      = (const float*)d_in[4];
    const float* W2      = (const float*)d_in[5];
    const float* a2      = (const float*)d_in[6];
    const float* W3      = (const float*)d_in[7];
    const float* a3      = (const float*)d_in[8];
    float* out = (float*)d_out;

    const int N = in_sizes[0] / 128;
    const int E = in_sizes[1];

    const int TB = (E + TILE_E - 1) / TILE_E;     // edge tiles
    const int NB = (N + 255) >> 8;                // buckets
    const int M  = NB * TB;

    // ---- workspace layout ----
    char* p = (char*)d_ws;
    float* zbuf    = (float*)p;  p += (size_t)N * 32 * sizeof(float);
    float* hbuf    = (float*)p;  p += (size_t)N * 32 * sizeof(float);
    float* s_src   = (float*)p;  p += (size_t)N * sizeof(float);
    float* s_dst   = (float*)p;  p += (size_t)N * sizeof(float);
    int*   offsets = (int*)p;    p += ((size_t)N + 1) * sizeof(int);
    int*   counts  = (int*)p;    p += ((size_t)M + 1) * sizeof(int);
    int*   cscan   = (int*)p;    p += ((size_t)M + 1) * sizeof(int);
    int*   blockSums = (int*)p;  p += 1024 * sizeof(int);
    int2*  ebuf    = (int2*)p;   p += (size_t)E * sizeof(int2);
    int*   csr_src = (int*)p;    p += (size_t)E * sizeof(int);

    const int nodeBlocks8  = (N + 7) / 8;
    const int nodeBlocks   = (N + 255) / 256;
    const int gemmBlocks64 = (N + 63) / 64;
    const int scanBlocksM  = (M + 255) / 256;

    // ---- build CSR: atomic-free two-level counting sort ----
    hipLaunchKernelGGL(csr_hist_kernel, dim3(TB), dim3(256), 0, stream,
                       dst, counts, E, TB, NB);
    hipLaunchKernelGGL(scan1_kernel, dim3(scanBlocksM), dim3(256), 0, stream,
                       counts, cscan, blockSums, M);
    hipLaunchKernelGGL(scan2_kernel, dim3(1), dim3(1024), 0, stream,
                       blockSums, scanBlocksM);
    hipLaunchKernelGGL(scan3_kernel, dim3(scanBlocksM), dim3(256), 0, stream,
                       counts, blockSums, cscan, M, E);
    hipLaunchKernelGGL(csr_scatter_kernel, dim3(TB), dim3(256), 0, stream,
                       src, dst, cscan, ebuf, E, TB, NB);
    hipLaunchKernelGGL(csr_bucket_kernel, dim3(NB), dim3(256), 0, stream,
                       ebuf, cscan, csr_src, offsets, N, E, TB);

    // ---- layer 1 (128 -> 32, relu) ----
    hipLaunchKernelGGL(gemm1_kernel, dim3(gemmBlocks64), dim3(128), 0, stream,
                       feature, W1, a1, zbuf, s_src, s_dst, N);
    hipLaunchKernelGGL(agg32_fused_kernel, dim3(nodeBlocks8), dim3(256), 0, stream,
                       offsets, csr_src, s_src, s_dst, zbuf, hbuf, N);

    // ---- layer 2 (32 -> 32, relu) ----
    hipLaunchKernelGGL(gemm2_kernel, dim3(gemmBlocks64), dim3(128), 0, stream,
                       hbuf, W2, a2, zbuf, s_src, s_dst, N);
    hipLaunchKernelGGL(agg32_fused_kernel, dim3(nodeBlocks8), dim3(256), 0, stream,
                       offsets, csr_src, s_src, s_dst, zbuf, hbuf, N);

    // ---- layer 3 (32 -> 1, sigmoid) ----
    float2* zs = (float2*)zbuf;
    hipLaunchKernelGGL(gemm3_kernel, dim3(nodeBlocks), dim3(256), 0, stream,
                       hbuf, W3, a3, zs, s_dst, N);
    hipLaunchKernelGGL(agg1_fused_kernel, dim3(nodeBlocks8), dim3(256), 0, stream,
                       offsets, csr_src, zs, s_dst, out, N);
}

// Round 11
// 276.846 us; speedup vs baseline: 1.7969x; 1.0138x over previous
//
#include <hip/hip_runtime.h>
#include <hip/hip_bf16.h>
#include <cstdint>
#include <cstddef>

#define NEG_SLOPE 0.01f

static __device__ __forceinline__ unsigned short f2bf(float f) {
    __hip_bfloat16 b = __float2bfloat16(f);   // RNE
    return *(unsigned short*)&b;
}
static __device__ __forceinline__ float bf2f(unsigned short u) {
    __hip_bfloat16 b = *(__hip_bfloat16*)&u;
    return __bfloat162float(b);
}

// ============================================================================
// GEMM kernels — register-blocked 4x4 micro-tiles.
// z is written in BF16 (agg reads it as a gather; halves gather bytes —
// threshold is 1e-2, bf16 error budget ~1e-3). Logits stay fp32.
// ============================================================================

__global__ __launch_bounds__(128) void gemm1_kernel(
    const float* __restrict__ h, const float* __restrict__ W,
    const float* __restrict__ a, unsigned short* __restrict__ zb,
    float* __restrict__ s_src, float* __restrict__ s_dst, int N)
{
    __shared__ float Wl[128 * 32];   // 16 KB only (occupancy: ~10 blocks/CU)
    int tid = threadIdx.x;
    int rowBase = blockIdx.x * 64;

    {
        const float4* W4 = (const float4*)W;
        float4* Wl4 = (float4*)Wl;
        for (int i = tid; i < 1024; i += 128) Wl4[i] = W4[i];
    }
    __syncthreads();

    int wv   = tid >> 6;
    int lane = tid & 63;
    int g    = lane >> 3;
    int l8   = lane & 7;
    int r0   = wv * 32 + g * 4;
    int col4 = l8 * 4;

    float acc[4][4];
#pragma unroll
    for (int i = 0; i < 4; i++)
#pragma unroll
        for (int c = 0; c < 4; c++) acc[i][c] = 0.f;

    const float4* h4  = (const float4*)h;     // row stride 32 float4
    const float4* Wl4 = (const float4*)Wl;

    size_t rowOff[4];
#pragma unroll
    for (int i = 0; i < 4; i++) {
        int r = rowBase + r0 + i;
        rowOff[i] = (size_t)((r < N) ? r : (N - 1)) * 32;
    }

#pragma unroll 2
    for (int kq = 0; kq < 32; kq++) {
        float4 w0 = Wl4[(kq * 4 + 0) * 8 + l8];
        float4 w1 = Wl4[(kq * 4 + 1) * 8 + l8];
        float4 w2 = Wl4[(kq * 4 + 2) * 8 + l8];
        float4 w3 = Wl4[(kq * 4 + 3) * 8 + l8];
#pragma unroll
        for (int i = 0; i < 4; i++) {
            float4 hv = h4[rowOff[i] + kq];   // global, broadcast across l8
            acc[i][0] += hv.x * w0.x; acc[i][1] += hv.x * w0.y;
            acc[i][2] += hv.x * w0.z; acc[i][3] += hv.x * w0.w;
            acc[i][0] += hv.y * w1.x; acc[i][1] += hv.y * w1.y;
            acc[i][2] += hv.y * w1.z; acc[i][3] += hv.y * w1.w;
            acc[i][0] += hv.z * w2.x; acc[i][1] += hv.z * w2.y;
            acc[i][2] += hv.z * w2.z; acc[i][3] += hv.z * w2.w;
            acc[i][0] += hv.w * w3.x; acc[i][1] += hv.w * w3.y;
            acc[i][2] += hv.w * w3.z; acc[i][3] += hv.w * w3.w;
        }
    }

    float4 alo = ((const float4*)a)[l8];
    float4 ahi = ((const float4*)a)[8 + l8];
#pragma unroll
    for (int i = 0; i < 4; i++) {
        int row = rowBase + r0 + i;
        if (row < N) {
            ushort4 zv4 = make_ushort4(f2bf(acc[i][0]), f2bf(acc[i][1]),
                                       f2bf(acc[i][2]), f2bf(acc[i][3]));
            *(ushort4*)&zb[(size_t)row * 32 + col4] = zv4;
            float ps = acc[i][0] * alo.x + acc[i][1] * alo.y + acc[i][2] * alo.z + acc[i][3] * alo.w;
            float pd = acc[i][0] * ahi.x + acc[i][1] * ahi.y + acc[i][2] * ahi.z + acc[i][3] * ahi.w;
            ps += __shfl_xor(ps, 1, 64); ps += __shfl_xor(ps, 2, 64); ps += __shfl_xor(ps, 4, 64);
            pd += __shfl_xor(pd, 1, 64); pd += __shfl_xor(pd, 2, 64); pd += __shfl_xor(pd, 4, 64);
            if (l8 == 0) { s_src[row] = ps; s_dst[row] = pd; }
        }
    }
}

__global__ __launch_bounds__(128) void gemm2_kernel(
    const float* __restrict__ h, const float* __restrict__ W,
    const float* __restrict__ a, unsigned short* __restrict__ zb,
    float* __restrict__ s_src, float* __restrict__ s_dst, int N)
{
    __shared__ float Hl[64 * 44];
    __shared__ float Wl[32 * 32];
    int tid = threadIdx.x;
    int rowBase = blockIdx.x * 64;

    {
        const float4* W4 = (const float4*)W;
        float4* Wl4 = (float4*)Wl;
        for (int i = tid; i < 256; i += 128) Wl4[i] = W4[i];
    }
    {
        const float4* h4 = (const float4*)h;
        for (int i = tid; i < 64 * 8; i += 128) {
            int r = i >> 3, kq = i & 7;
            float4 v = (rowBase + r < N) ? h4[(size_t)(rowBase + r) * 8 + kq]
                                         : make_float4(0.f, 0.f, 0.f, 0.f);
            *(float4*)&Hl[r * 44 + kq * 4] = v;
        }
    }
    __syncthreads();

    int wv   = tid >> 6;
    int lane = tid & 63;
    int g    = lane >> 3;
    int l8   = lane & 7;
    int r0   = wv * 32 + g * 4;
    int col4 = l8 * 4;

    float acc[4][4];
#pragma unroll
    for (int i = 0; i < 4; i++)
#pragma unroll
        for (int c = 0; c < 4; c++) acc[i][c] = 0.f;

    const float4* H4  = (const float4*)Hl;
    const float4* Wl4 = (const float4*)Wl;

#pragma unroll
    for (int kq = 0; kq < 8; kq++) {
        float4 w0 = Wl4[(kq * 4 + 0) * 8 + l8];
        float4 w1 = Wl4[(kq * 4 + 1) * 8 + l8];
        float4 w2 = Wl4[(kq * 4 + 2) * 8 + l8];
        float4 w3 = Wl4[(kq * 4 + 3) * 8 + l8];
#pragma unroll
        for (int i = 0; i < 4; i++) {
            float4 hv = H4[(r0 + i) * 11 + kq];
            acc[i][0] += hv.x * w0.x; acc[i][1] += hv.x * w0.y;
            acc[i][2] += hv.x * w0.z; acc[i][3] += hv.x * w0.w;
            acc[i][0] += hv.y * w1.x; acc[i][1] += hv.y * w1.y;
            acc[i][2] += hv.y * w1.z; acc[i][3] += hv.y * w1.w;
            acc[i][0] += hv.z * w2.x; acc[i][1] += hv.z * w2.y;
            acc[i][2] += hv.z * w2.z; acc[i][3] += hv.z * w2.w;
            acc[i][0] += hv.w * w3.x; acc[i][1] += hv.w * w3.y;
            acc[i][2] += hv.w * w3.z; acc[i][3] += hv.w * w3.w;
        }
    }

    float4 alo = ((const float4*)a)[l8];
    float4 ahi = ((const float4*)a)[8 + l8];
#pragma unroll
    for (int i = 0; i < 4; i++) {
        int row = rowBase + r0 + i;
        if (row < N) {
            ushort4 zv4 = make_ushort4(f2bf(acc[i][0]), f2bf(acc[i][1]),
                                       f2bf(acc[i][2]), f2bf(acc[i][3]));
            *(ushort4*)&zb[(size_t)row * 32 + col4] = zv4;
            float ps = acc[i][0] * alo.x + acc[i][1] * alo.y + acc[i][2] * alo.z + acc[i][3] * alo.w;
            float pd = acc[i][0] * ahi.x + acc[i][1] * ahi.y + acc[i][2] * ahi.z + acc[i][3] * ahi.w;
            ps += __shfl_xor(ps, 1, 64); ps += __shfl_xor(ps, 2, 64); ps += __shfl_xor(ps, 4, 64);
            pd += __shfl_xor(pd, 1, 64); pd += __shfl_xor(pd, 2, 64); pd += __shfl_xor(pd, 4, 64);
            if (l8 == 0) { s_src[row] = ps; s_dst[row] = pd; }
        }
    }
}

// layer 3: zs[i] = {z, z*a0} interleaved (single-line fp32 gather in agg1)
__global__ __launch_bounds__(256) void gemm3_kernel(
    const float* __restrict__ h, const float* __restrict__ W,
    const float* __restrict__ a, float2* __restrict__ zs,
    float* __restrict__ s_dst, int N)
{
    int i = blockIdx.x * 256 + threadIdx.x;
    if (i >= N) return;
    const float4* hp = (const float4*)(h + (size_t)i * 32);
    const float4* wp = (const float4*)W;
    float acc = 0.f;
#pragma unroll
    for (int c = 0; c < 8; c++) {
        float4 v = hp[c];
        float4 w = wp[c];
        acc += v.x * w.x + v.y * w.y + v.z * w.z + v.w * w.w;
    }
    zs[i] = make_float2(acc, acc * a[0]);
    s_dst[i] = acc * a[1];
}

// ============================================================================
// Atomic-free CSR build: two-level counting sort by dst (LDS atomics only).
// ebuf entry packed into one int: (src << 8) | (dst & 255)  [src < 2^24].
// ============================================================================

#define TILE_E 4096
#define NB_MAX 512     // supports N <= 131072

__global__ __launch_bounds__(256) void csr_hist_kernel(
    const int* __restrict__ dst, int* __restrict__ counts,
    int E, int TB, int NB)
{
    __shared__ int hist[NB_MAX];
    int tid = threadIdx.x;
    int t = blockIdx.x;
    for (int b = tid; b < NB; b += 256) hist[b] = 0;
    __syncthreads();
    int base = t * TILE_E;
    for (int i = tid; i < TILE_E; i += 256) {
        int k = base + i;
        if (k < E) atomicAdd(&hist[dst[k] >> 8], 1);
    }
    __syncthreads();
    for (int b = tid; b < NB; b += 256) counts[b * TB + t] = hist[b];
}

__global__ __launch_bounds__(256) void scan1_kernel(
    const int* __restrict__ vals, int* __restrict__ incl,
    int* __restrict__ blockSums, int M)
{
    __shared__ int tmp[256];
    int tid = threadIdx.x;
    int i = blockIdx.x * 256 + tid;
    int v = (i < M) ? vals[i] : 0;
    tmp[tid] = v;
    __syncthreads();
#pragma unroll
    for (int off = 1; off < 256; off <<= 1) {
        int t = (tid >= off) ? tmp[tid - off] : 0;
        __syncthreads();
        tmp[tid] += t;
        __syncthreads();
    }
    if (i < M) incl[i] = tmp[tid];
    if (tid == 255) blockSums[blockIdx.x] = tmp[255];
}

__global__ __launch_bounds__(1024) void scan2_kernel(int* __restrict__ blockSums, int nb)
{
    __shared__ int tmp[1024];
    int tid = threadIdx.x;
    int v = (tid < nb) ? blockSums[tid] : 0;
    tmp[tid] = v;
    __syncthreads();
#pragma unroll
    for (int off = 1; off < 1024; off <<= 1) {
        int t = (tid >= off) ? tmp[tid - off] : 0;
        __syncthreads();
        tmp[tid] += t;
        __syncthreads();
    }
    if (tid < nb) blockSums[tid] = tmp[tid] - v;  // exclusive
}

__global__ __launch_bounds__(256) void scan3_kernel(
    const int* __restrict__ vals, const int* __restrict__ blockSums,
    int* __restrict__ cscan, int M, int E)
{
    int i = blockIdx.x * 256 + threadIdx.x;
    if (i < M) {
        cscan[i] = cscan[i] - vals[i] + blockSums[i >> 8];
    }
    if (i == 0) cscan[M] = E;
}

__global__ __launch_bounds__(256) void csr_scatter_kernel(
    const int* __restrict__ src, const int* __restrict__ dst,
    const int* __restrict__ cscan, int* __restrict__ ebuf,
    int E, int TB, int NB)
{
    __shared__ int baseB[NB_MAX];
    __shared__ int cur[NB_MAX];
    int tid = threadIdx.x;
    int t = blockIdx.x;
    for (int b = tid; b < NB; b += 256) {
        baseB[b] = cscan[b * TB + t];
        cur[b] = 0;
    }
    __syncthreads();
    int base = t * TILE_E;
    for (int i = tid; i < TILE_E; i += 256) {
        int k = base + i;
        if (k < E) {
            int d = dst[k], s = src[k];
            int b = d >> 8;
            int r = atomicAdd(&cur[b], 1);
            ebuf[baseB[b] + r] = (s << 8) | (d & 255);
        }
    }
}

__global__ __launch_bounds__(256) void csr_bucket_kernel(
    const int* __restrict__ ebuf, const int* __restrict__ cscan,
    int* __restrict__ csr_src, int* __restrict__ offsets,
    int N, int E, int TB)
{
    __shared__ int eb[8192];      // 32KB staging
    __shared__ int hist[256];
    __shared__ int loff[256];
    __shared__ int tmp[256];
    int tid = threadIdx.x;
    int b = blockIdx.x;

    int beg = cscan[b * TB];
    int endv = cscan[(b + 1) * TB];
    int cnt = endv - beg;
    int first = b << 8;

    hist[tid] = 0;
    __syncthreads();

    bool inLds = (cnt <= 8192);
    for (int i = tid; i < cnt; i += 256) {
        int v = ebuf[beg + i];
        if (inLds) eb[i] = v;
        atomicAdd(&hist[v & 255], 1);
    }
    __syncthreads();

    int hv = hist[tid];
    tmp[tid] = hv;
    __syncthreads();
#pragma unroll
    for (int off = 1; off < 256; off <<= 1) {
        int t = (tid >= off) ? tmp[tid - off] : 0;
        __syncthreads();
        tmp[tid] += t;
        __syncthreads();
    }
    loff[tid] = tmp[tid] - hv;
    __syncthreads();

    if (first + tid < N) offsets[first + tid] = beg + loff[tid];
    if (b == 0 && tid == 0) offsets[N] = E;

    hist[tid] = 0;
    __syncthreads();

    for (int i = tid; i < cnt; i += 256) {
        int v = inLds ? eb[i] : ebuf[beg + i];
        int d8 = v & 255;
        int r = atomicAdd(&hist[d8], 1);
        csr_src[beg + loff[d8] + r] = v >> 8;   // s (non-negative)
    }
}

// ============================================================================
// Fused softmax + aggregation. 32-lane group per node. z gathered as BF16.
// ============================================================================

__global__ __launch_bounds__(256) void agg32_fused_kernel(
    const int* __restrict__ offsets, const int* __restrict__ csr_src,
    const float* __restrict__ s_src, const float* __restrict__ s_dst,
    const unsigned short* __restrict__ zb, float* __restrict__ h, int N)
{
    __shared__ float2 wsbuf[8 * 128];   // 8 groups x 128 edges x {w, s}
    int g    = threadIdx.x >> 5;
    int lane = threadIdx.x & 31;
    int node = blockIdx.x * 8 + g;
    if (node >= N) return;
    float2* ws = &wsbuf[g * 128];

    int beg = offsets[node], end = offsets[node + 1];
    int deg = end - beg;
    float sd = s_dst[node];
    float o = 0.f;
    float rden;

    if (deg <= 128) {
        int   sreg[4];
        float ev[4];
        int nIter = (deg + 31) >> 5;
        float m = -3.0e38f;
#pragma unroll 4
        for (int it = 0; it < nIter; ++it) {
            int p = beg + it * 32 + lane;
            float e = -3.0e38f;
            int s = 0;
            if (p < end) {
                s = csr_src[p];
                e = s_src[s] + sd;
                e = (e > 0.f) ? e : NEG_SLOPE * e;
            }
            sreg[it] = s;
            ev[it] = e;
            m = fmaxf(m, e);
        }
#pragma unroll
        for (int off = 16; off > 0; off >>= 1) m = fmaxf(m, __shfl_xor(m, off, 32));

        float l = 0.f;
#pragma unroll 4
        for (int it = 0; it < nIter; ++it) {
            int p = beg + it * 32 + lane;
            float w = (p < end) ? __expf(ev[it] - m) : 0.f;
            ws[it * 32 + lane] = make_float2(w, __int_as_float(sreg[it]));
            l += w;
        }
#pragma unroll
        for (int off = 16; off > 0; off >>= 1) l += __shfl_xor(l, off, 32);
        rden = 1.f / fmaxf(l, 1e-9f);

        // phase B: branch-free, 4 independent bf16 gathers in flight
        int p = 0;
        for (; p + 4 <= deg; p += 4) {
            float2 a0 = ws[p],     a1 = ws[p + 1];
            float2 a2 = ws[p + 2], a3 = ws[p + 3];
            int s0 = __float_as_int(a0.y), s1 = __float_as_int(a1.y);
            int s2 = __float_as_int(a2.y), s3 = __float_as_int(a3.y);
            unsigned short u0 = zb[(size_t)s0 * 32 + lane];
            unsigned short u1 = zb[(size_t)s1 * 32 + lane];
            unsigned short u2 = zb[(size_t)s2 * 32 + lane];
            unsigned short u3 = zb[(size_t)s3 * 32 + lane];
            o += a0.x * bf2f(u0);
            o += a1.x * bf2f(u1);
            o += a2.x * bf2f(u2);
            o += a3.x * bf2f(u3);
        }
        for (; p < deg; ++p) {
            float2 aa = ws[p];
            o += aa.x * bf2f(zb[(size_t)__float_as_int(aa.y) * 32 + lane]);
        }
    } else {
        float m = -3.0e38f;
        for (int p = beg + lane; p < end; p += 32) {
            float e = s_src[csr_src[p]] + sd;
            e = (e > 0.f) ? e : NEG_SLOPE * e;
            m = fmaxf(m, e);
        }
#pragma unroll
        for (int off = 16; off > 0; off >>= 1) m = fmaxf(m, __shfl_xor(m, off, 32));
        float l = 0.f;
        for (int p = beg + lane; p < end; p += 32) {
            float e = s_src[csr_src[p]] + sd;
            e = (e > 0.f) ? e : NEG_SLOPE * e;
            l += __expf(e - m);
        }
#pragma unroll
        for (int off = 16; off > 0; off >>= 1) l += __shfl_xor(l, off, 32);
        rden = 1.f / fmaxf(l, 1e-9f);
        for (int p = beg; p < end; ++p) {
            int s = csr_src[p];                    // uniform
            float e = s_src[s] + sd;
            e = (e > 0.f) ? e : NEG_SLOPE * e;
            float w = __expf(e - m);
            o += w * bf2f(zb[(size_t)s * 32 + lane]);
        }
    }

    float v = o * rden;
    h[(size_t)node * 32 + lane] = (v > 0.f) ? v : 0.f;  // relu
}

// d_out = 1: fully edge-parallel, one 8B fp32 gather per edge, fused sigmoid
__global__ __launch_bounds__(256) void agg1_fused_kernel(
    const int* __restrict__ offsets, const int* __restrict__ csr_src,
    const float2* __restrict__ zs, const float* __restrict__ s_dst,
    float* __restrict__ out, int N)
{
    int node = blockIdx.x * 8 + (threadIdx.x >> 5);
    int lane = threadIdx.x & 31;
    if (node >= N) return;

    int beg = offsets[node], end = offsets[node + 1];
    int deg = end - beg;
    float sd = s_dst[node];

    if (deg <= 128) {
        float ev[4], zv[4];
        int nIter = (deg + 31) >> 5;
        float m = -3.0e38f;
#pragma unroll 4
        for (int it = 0; it < nIter; ++it) {
            int p = beg + it * 32 + lane;
            float e = -3.0e38f, zz = 0.f;
            if (p < end) {
                float2 v2 = zs[csr_src[p]];
                zz = v2.x;
                e = v2.y + sd;
                e = (e > 0.f) ? e : NEG_SLOPE * e;
            }
            ev[it] = e; zv[it] = zz;
            m = fmaxf(m, e);
        }
#pragma unroll
        for (int off = 16; off > 0; off >>= 1) m = fmaxf(m, __shfl_xor(m, off, 32));
        float l = 0.f, o = 0.f;
#pragma unroll 4
        for (int it = 0; it < nIter; ++it) {
            int p = beg + it * 32 + lane;
            float w = (p < end) ? __expf(ev[it] - m) : 0.f;
            l += w;
            o += w * zv[it];
        }
#pragma unroll
        for (int off = 16; off > 0; off >>= 1) {
            l += __shfl_xor(l, off, 32);
            o += __shfl_xor(o, off, 32);
        }
        if (lane == 0) {
            float v = o / fmaxf(l, 1e-9f);
            out[node] = 1.f / (1.f + __expf(-v));
        }
    } else {
        float m = -3.0e38f;
        for (int p = beg + lane; p < end; p += 32) {
            float e = zs[csr_src[p]].y + sd;
            e = (e > 0.f) ? e : NEG_SLOPE * e;
            m = fmaxf(m, e);
        }
#pragma unroll
        for (int off = 16; off > 0; off >>= 1) m = fmaxf(m, __shfl_xor(m, off, 32));
        float l = 0.f, o = 0.f;
        for (int p = beg + lane; p < end; p += 32) {
            float2 v2 = zs[csr_src[p]];
            float e = v2.y + sd;
            e = (e > 0.f) ? e : NEG_SLOPE * e;
            float w = __expf(e - m);
            l += w; o += w * v2.x;
        }
#pragma unroll
        for (int off = 16; off > 0; off >>= 1) {
            l += __shfl_xor(l, off, 32);
            o += __shfl_xor(o, off, 32);
        }
        if (lane == 0) {
            float v = o / fmaxf(l, 1e-9f);
            out[node] = 1.f / (1.f + __expf(-v));
        }
    }
}

// ============================================================================

extern "C" void kernel_launch(void* const* d_in, const int* in_sizes, int n_in,
                              void* d_out, int out_size, void* d_ws, size_t ws_size,
                              hipStream_t stream)
{
    const float* feature = (const float*)d_in[0];
    const int*   src     = (const int*)d_in[1];
    const int*   dst     = (const int*)d_in[2];
    const float* W1      = (const float*)d_in[3];
    const float* a1      = (const float*)d_in[4];
    const float* W2      = (const float*)d_in[5];
    const float* a2      = (const float*)d_in[6];
    const float* W3      = (const float*)d_in[7];
    const float* a3      = (const float*)d_in[8];
    float* out = (float*)d_out;

    const int N = in_sizes[0] / 128;
    const int E = in_sizes[1];

    const int TB = (E + TILE_E - 1) / TILE_E;     // edge tiles
    const int NB = (N + 255) >> 8;                // buckets
    const int M  = NB * TB;

    // ---- workspace layout ----
    char* p = (char*)d_ws;
    unsigned short* zb = (unsigned short*)p;  p += (size_t)N * 32 * sizeof(unsigned short);
    float* hbuf    = (float*)p;  p += (size_t)N * 32 * sizeof(float);
    float* zs32    = (float*)p;  p += (size_t)N * 2 * sizeof(float);   // layer-3 {z, z*a0}
    float* s_src   = (float*)p;  p += (size_t)N * sizeof(float);
    float* s_dst   = (float*)p;  p += (size_t)N * sizeof(float);
    int*   offsets = (int*)p;    p += ((size_t)N + 1) * sizeof(int);
    int*   counts  = (int*)p;    p += ((size_t)M + 1) * sizeof(int);
    int*   cscan   = (int*)p;    p += ((size_t)M + 1) * sizeof(int);
    int*   blockSums = (int*)p;  p += 1024 * sizeof(int);
    int*   ebuf    = (int*)p;    p += (size_t)E * sizeof(int);
    int*   csr_src = (int*)p;    p += (size_t)E * sizeof(int);

    const int nodeBlocks8  = (N + 7) / 8;
    const int nodeBlocks   = (N + 255) / 256;
    const int gemmBlocks64 = (N + 63) / 64;
    const int scanBlocksM  = (M + 255) / 256;

    // ---- build CSR: atomic-free two-level counting sort ----
    hipLaunchKernelGGL(csr_hist_kernel, dim3(TB), dim3(256), 0, stream,
                       dst, counts, E, TB, NB);
    hipLaunchKernelGGL(scan1_kernel, dim3(scanBlocksM), dim3(256), 0, stream,
                       counts, cscan, blockSums, M);
    hipLaunchKernelGGL(scan2_kernel, dim3(1), dim3(1024), 0, stream,
                       blockSums, scanBlocksM);
    hipLaunchKernelGGL(scan3_kernel, dim3(scanBlocksM), dim3(256), 0, stream,
                       counts, blockSums, cscan, M, E);
    hipLaunchKernelGGL(csr_scatter_kernel, dim3(TB), dim3(256), 0, stream,
                       src, dst, cscan, ebuf, E, TB, NB);
    hipLaunchKernelGGL(csr_bucket_kernel, dim3(NB), dim3(256), 0, stream,
                       ebuf, cscan, csr_src, offsets, N, E, TB);

    // ---- layer 1 (128 -> 32, relu) ----
    hipLaunchKernelGGL(gemm1_kernel, dim3(gemmBlocks64), dim3(128), 0, stream,
                       feature, W1, a1, zb, s_src, s_dst, N);
    hipLaunchKernelGGL(agg32_fused_kernel, dim3(nodeBlocks8), dim3(256), 0, stream,
                       offsets, csr_src, s_src, s_dst, zb, hbuf, N);

    // ---- layer 2 (32 -> 32, relu) ----
    hipLaunchKernelGGL(gemm2_kernel, dim3(gemmBlocks64), dim3(128), 0, stream,
                       hbuf, W2, a2, zb, s_src, s_dst, N);
    hipLaunchKernelGGL(agg32_fused_kernel, dim3(nodeBlocks8), dim3(256), 0, stream,
                       offsets, csr_src, s_src, s_dst, zb, hbuf, N);

    // ---- layer 3 (32 -> 1, sigmoid) ----
    float2* zs = (float2*)zs32;
    hipLaunchKernelGGL(gemm3_kernel, dim3(nodeBlocks), dim3(256), 0, stream,
                       hbuf, W3, a3, zs, s_dst, N);
    hipLaunchKernelGGL(agg1_fused_kernel, dim3(nodeBlocks8), dim3(256), 0, stream,
                       offsets, csr_src, zs, s_dst, out, N);
}

// Round 12
// 272.792 us; speedup vs baseline: 1.8236x; 1.0149x over previous
//
#include <hip/hip_runtime.h>
#include <hip/hip_bf16.h>
#include <cstdint>
#include <cstddef>

#define NEG_SLOPE 0.01f

static __device__ __forceinline__ unsigned short f2bf(float f) {
    __hip_bfloat16 b = __float2bfloat16(f);   // RNE
    return *(unsigned short*)&b;
}
static __device__ __forceinline__ float bf2f(unsigned short u) {
    __hip_bfloat16 b = *(__hip_bfloat16*)&u;
    return __bfloat162float(b);
}

// ============================================================================
// Layer-1 GEMM: z1 = feature[N,128] @ W1[128,32] (bf16 out) + fp32 logits.
// 128 threads, 64 rows/block, h read direct from global (broadcast across
// the 8-lane col-group; 16KB LDS only -> high occupancy, R9/R10 lesson).
// ============================================================================

__global__ __launch_bounds__(128) void gemm1_kernel(
    const float* __restrict__ h, const float* __restrict__ W,
    const float* __restrict__ a, unsigned short* __restrict__ zb,
    float* __restrict__ s_src, float* __restrict__ s_dst, int N)
{
    __shared__ float Wl[128 * 32];
    int tid = threadIdx.x;
    int rowBase = blockIdx.x * 64;

    {
        const float4* W4 = (const float4*)W;
        float4* Wl4 = (float4*)Wl;
        for (int i = tid; i < 1024; i += 128) Wl4[i] = W4[i];
    }
    __syncthreads();

    int wv   = tid >> 6;
    int lane = tid & 63;
    int g    = lane >> 3;
    int l8   = lane & 7;
    int r0   = wv * 32 + g * 4;
    int col4 = l8 * 4;

    float acc[4][4];
#pragma unroll
    for (int i = 0; i < 4; i++)
#pragma unroll
        for (int c = 0; c < 4; c++) acc[i][c] = 0.f;

    const float4* h4  = (const float4*)h;
    const float4* Wl4 = (const float4*)Wl;

    size_t rowOff[4];
#pragma unroll
    for (int i = 0; i < 4; i++) {
        int r = rowBase + r0 + i;
        rowOff[i] = (size_t)((r < N) ? r : (N - 1)) * 32;
    }

#pragma unroll 2
    for (int kq = 0; kq < 32; kq++) {
        float4 w0 = Wl4[(kq * 4 + 0) * 8 + l8];
        float4 w1 = Wl4[(kq * 4 + 1) * 8 + l8];
        float4 w2 = Wl4[(kq * 4 + 2) * 8 + l8];
        float4 w3 = Wl4[(kq * 4 + 3) * 8 + l8];
#pragma unroll
        for (int i = 0; i < 4; i++) {
            float4 hv = h4[rowOff[i] + kq];
            acc[i][0] += hv.x * w0.x; acc[i][1] += hv.x * w0.y;
            acc[i][2] += hv.x * w0.z; acc[i][3] += hv.x * w0.w;
            acc[i][0] += hv.y * w1.x; acc[i][1] += hv.y * w1.y;
            acc[i][2] += hv.y * w1.z; acc[i][3] += hv.y * w1.w;
            acc[i][0] += hv.z * w2.x; acc[i][1] += hv.z * w2.y;
            acc[i][2] += hv.z * w2.z; acc[i][3] += hv.z * w2.w;
            acc[i][0] += hv.w * w3.x; acc[i][1] += hv.w * w3.y;
            acc[i][2] += hv.w * w3.z; acc[i][3] += hv.w * w3.w;
        }
    }

    float4 alo = ((const float4*)a)[l8];
    float4 ahi = ((const float4*)a)[8 + l8];
#pragma unroll
    for (int i = 0; i < 4; i++) {
        int row = rowBase + r0 + i;
        if (row < N) {
            ushort4 zv4 = make_ushort4(f2bf(acc[i][0]), f2bf(acc[i][1]),
                                       f2bf(acc[i][2]), f2bf(acc[i][3]));
            *(ushort4*)&zb[(size_t)row * 32 + col4] = zv4;
            float ps = acc[i][0] * alo.x + acc[i][1] * alo.y + acc[i][2] * alo.z + acc[i][3] * alo.w;
            float pd = acc[i][0] * ahi.x + acc[i][1] * ahi.y + acc[i][2] * ahi.z + acc[i][3] * ahi.w;
            ps += __shfl_xor(ps, 1, 64); ps += __shfl_xor(ps, 2, 64); ps += __shfl_xor(ps, 4, 64);
            pd += __shfl_xor(pd, 1, 64); pd += __shfl_xor(pd, 2, 64); pd += __shfl_xor(pd, 4, 64);
            if (l8 == 0) { s_src[row] = ps; s_dst[row] = pd; }
        }
    }
}

// ============================================================================
// Atomic-free CSR build: two-level counting sort by dst (LDS atomics only).
// ebuf entry packed: (src << 8) | (dst & 255), src < 2^24.
// ============================================================================

#define TILE_E 4096
#define NB_MAX 512     // supports N <= 131072

__global__ __launch_bounds__(256) void csr_hist_kernel(
    const int* __restrict__ dst, int* __restrict__ counts,
    int E, int TB, int NB)
{
    __shared__ int hist[NB_MAX];
    int tid = threadIdx.x;
    int t = blockIdx.x;
    for (int b = tid; b < NB; b += 256) hist[b] = 0;
    __syncthreads();
    int base = t * TILE_E;
    for (int i = tid; i < TILE_E; i += 256) {
        int k = base + i;
        if (k < E) atomicAdd(&hist[dst[k] >> 8], 1);
    }
    __syncthreads();
    for (int b = tid; b < NB; b += 256) counts[b * TB + t] = hist[b];
}

__global__ __launch_bounds__(256) void scan1_kernel(
    const int* __restrict__ vals, int* __restrict__ incl,
    int* __restrict__ blockSums, int M)
{
    __shared__ int tmp[256];
    int tid = threadIdx.x;
    int i = blockIdx.x * 256 + tid;
    int v = (i < M) ? vals[i] : 0;
    tmp[tid] = v;
    __syncthreads();
#pragma unroll
    for (int off = 1; off < 256; off <<= 1) {
        int t = (tid >= off) ? tmp[tid - off] : 0;
        __syncthreads();
        tmp[tid] += t;
        __syncthreads();
    }
    if (i < M) incl[i] = tmp[tid];
    if (tid == 255) blockSums[blockIdx.x] = tmp[255];
}

__global__ __launch_bounds__(1024) void scan2_kernel(int* __restrict__ blockSums, int nb)
{
    __shared__ int tmp[1024];
    int tid = threadIdx.x;
    int v = (tid < nb) ? blockSums[tid] : 0;
    tmp[tid] = v;
    __syncthreads();
#pragma unroll
    for (int off = 1; off < 1024; off <<= 1) {
        int t = (tid >= off) ? tmp[tid - off] : 0;
        __syncthreads();
        tmp[tid] += t;
        __syncthreads();
    }
    if (tid < nb) blockSums[tid] = tmp[tid] - v;  // exclusive
}

__global__ __launch_bounds__(256) void scan3_kernel(
    const int* __restrict__ vals, const int* __restrict__ blockSums,
    int* __restrict__ cscan, int M, int E)
{
    int i = blockIdx.x * 256 + threadIdx.x;
    if (i < M) {
        cscan[i] = cscan[i] - vals[i] + blockSums[i >> 8];
    }
    if (i == 0) cscan[M] = E;
}

__global__ __launch_bounds__(256) void csr_scatter_kernel(
    const int* __restrict__ src, const int* __restrict__ dst,
    const int* __restrict__ cscan, int* __restrict__ ebuf,
    int E, int TB, int NB)
{
    __shared__ int baseB[NB_MAX];
    __shared__ int cur[NB_MAX];
    int tid = threadIdx.x;
    int t = blockIdx.x;
    for (int b = tid; b < NB; b += 256) {
        baseB[b] = cscan[b * TB + t];
        cur[b] = 0;
    }
    __syncthreads();
    int base = t * TILE_E;
    for (int i = tid; i < TILE_E; i += 256) {
        int k = base + i;
        if (k < E) {
            int d = dst[k], s = src[k];
            int b = d >> 8;
            int r = atomicAdd(&cur[b], 1);
            ebuf[baseB[b] + r] = (s << 8) | (d & 255);
        }
    }
}

__global__ __launch_bounds__(256) void csr_bucket_kernel(
    const int* __restrict__ ebuf, const int* __restrict__ cscan,
    int* __restrict__ csr_src, int* __restrict__ offsets,
    int N, int E, int TB)
{
    __shared__ int eb[8192];      // 32KB staging
    __shared__ int hist[256];
    __shared__ int loff[256];
    __shared__ int tmp[256];
    int tid = threadIdx.x;
    int b = blockIdx.x;

    int beg = cscan[b * TB];
    int endv = cscan[(b + 1) * TB];
    int cnt = endv - beg;
    int first = b << 8;

    hist[tid] = 0;
    __syncthreads();

    bool inLds = (cnt <= 8192);
    for (int i = tid; i < cnt; i += 256) {
        int v = ebuf[beg + i];
        if (inLds) eb[i] = v;
        atomicAdd(&hist[v & 255], 1);
    }
    __syncthreads();

    int hv = hist[tid];
    tmp[tid] = hv;
    __syncthreads();
#pragma unroll
    for (int off = 1; off < 256; off <<= 1) {
        int t = (tid >= off) ? tmp[tid - off] : 0;
        __syncthreads();
        tmp[tid] += t;
        __syncthreads();
    }
    loff[tid] = tmp[tid] - hv;
    __syncthreads();

    if (first + tid < N) offsets[first + tid] = beg + loff[tid];
    if (b == 0 && tid == 0) offsets[N] = E;

    hist[tid] = 0;
    __syncthreads();

    for (int i = tid; i < cnt; i += 256) {
        int v = inLds ? eb[i] : ebuf[beg + i];
        int d8 = v & 255;
        int r = atomicAdd(&hist[d8], 1);
        csr_src[beg + loff[d8] + r] = v >> 8;
    }
}

// ============================================================================
// Gather core macro: fused softmax + weighted bf16 aggregation for one node
// per 32-lane group. Produces `v` = relu(sum(alpha*z)) per (node, lane).
// Phase A: edge-parallel logits + shuffle-reduced max/denom; (w,s) spilled
// to per-group LDS. Phase B: branch-free 8-wide unrolled gather.
// ============================================================================

#define AGG32_CORE(S_SRC, S_DST, ZB)                                          \
    int beg = offsets[node], end = offsets[node + 1];                         \
    int deg = end - beg;                                                      \
    float sd = (S_DST)[node];                                                 \
    float o = 0.f;                                                            \
    float rden;                                                               \
    if (deg <= 128) {                                                         \
        int   sreg[4];                                                        \
        float ev[4];                                                          \
        int nIter = (deg + 31) >> 5;                                          \
        float m = -3.0e38f;                                                   \
        _Pragma("unroll 4")                                                   \
        for (int it = 0; it < nIter; ++it) {                                  \
            int p = beg + it * 32 + lane;                                     \
            float e = -3.0e38f;                                               \
            int s = 0;                                                        \
            if (p < end) {                                                    \
                s = csr_src[p];                                               \
                e = (S_SRC)[s] + sd;                                          \
                e = (e > 0.f) ? e : NEG_SLOPE * e;                            \
            }                                                                 \
            sreg[it] = s;                                                     \
            ev[it] = e;                                                       \
            m = fmaxf(m, e);                                                  \
        }                                                                     \
        _Pragma("unroll")                                                     \
        for (int off = 16; off > 0; off >>= 1)                                \
            m = fmaxf(m, __shfl_xor(m, off, 32));                             \
        float l = 0.f;                                                        \
        _Pragma("unroll 4")                                                   \
        for (int it = 0; it < nIter; ++it) {                                  \
            int p = beg + it * 32 + lane;                                     \
            float w = (p < end) ? __expf(ev[it] - m) : 0.f;                   \
            ws[it * 32 + lane] = make_float2(w, __int_as_float(sreg[it]));    \
            l += w;                                                           \
        }                                                                     \
        _Pragma("unroll")                                                     \
        for (int off = 16; off > 0; off >>= 1) l += __shfl_xor(l, off, 32);   \
        rden = 1.f / fmaxf(l, 1e-9f);                                         \
        int p = 0;                                                            \
        for (; p + 8 <= deg; p += 8) {                                        \
            float2 a0 = ws[p],     a1 = ws[p + 1];                            \
            float2 a2 = ws[p + 2], a3 = ws[p + 3];                            \
            float2 a4 = ws[p + 4], a5 = ws[p + 5];                            \
            float2 a6 = ws[p + 6], a7 = ws[p + 7];                            \
            unsigned short u0 = (ZB)[(size_t)__float_as_int(a0.y) * 32 + lane]; \
            unsigned short u1 = (ZB)[(size_t)__float_as_int(a1.y) * 32 + lane]; \
            unsigned short u2 = (ZB)[(size_t)__float_as_int(a2.y) * 32 + lane]; \
            unsigned short u3 = (ZB)[(size_t)__float_as_int(a3.y) * 32 + lane]; \
            unsigned short u4 = (ZB)[(size_t)__float_as_int(a4.y) * 32 + lane]; \
            unsigned short u5 = (ZB)[(size_t)__float_as_int(a5.y) * 32 + lane]; \
            unsigned short u6 = (ZB)[(size_t)__float_as_int(a6.y) * 32 + lane]; \
            unsigned short u7 = (ZB)[(size_t)__float_as_int(a7.y) * 32 + lane]; \
            o += a0.x * bf2f(u0); o += a1.x * bf2f(u1);                       \
            o += a2.x * bf2f(u2); o += a3.x * bf2f(u3);                       \
            o += a4.x * bf2f(u4); o += a5.x * bf2f(u5);                       \
            o += a6.x * bf2f(u6); o += a7.x * bf2f(u7);                       \
        }                                                                     \
        for (; p < deg; ++p) {                                                \
            float2 aa = ws[p];                                                \
            o += aa.x * bf2f((ZB)[(size_t)__float_as_int(aa.y) * 32 + lane]); \
        }                                                                     \
    } else {                                                                  \
        float m = -3.0e38f;                                                   \
        for (int p = beg + lane; p < end; p += 32) {                          \
            float e = (S_SRC)[csr_src[p]] + sd;                               \
            e = (e > 0.f) ? e : NEG_SLOPE * e;                                \
            m = fmaxf(m, e);                                                  \
        }                                                                     \
        _Pragma("unroll")                                                     \
        for (int off = 16; off > 0; off >>= 1)                                \
            m = fmaxf(m, __shfl_xor(m, off, 32));                             \
        float l = 0.f;                                                        \
        for (int p = beg + lane; p < end; p += 32) {                          \
            float e = (S_SRC)[csr_src[p]] + sd;                               \
            e = (e > 0.f) ? e : NEG_SLOPE * e;                                \
            l += __expf(e - m);                                               \
        }                                                                     \
        _Pragma("unroll")                                                     \
        for (int off = 16; off > 0; off >>= 1) l += __shfl_xor(l, off, 32);   \
        rden = 1.f / fmaxf(l, 1e-9f);                                         \
        for (int p = beg; p < end; ++p) {                                     \
            int s = csr_src[p];                                               \
            float e = (S_SRC)[s] + sd;                                        \
            e = (e > 0.f) ? e : NEG_SLOPE * e;                                \
            float w = __expf(e - m);                                          \
            o += w * bf2f((ZB)[(size_t)s * 32 + lane]);                       \
        }                                                                     \
    }                                                                         \
    float v = o * rden;                                                       \
    v = (v > 0.f) ? v : 0.f;   /* relu */

// ---- layer 1 agg, fused with gemm2 epilogue: emits z2 (bf16) + logits ----
__global__ __launch_bounds__(256) void agg32_l1_kernel(
    const int* __restrict__ offsets, const int* __restrict__ csr_src,
    const float* __restrict__ s_src1, const float* __restrict__ s_dst1,
    const unsigned short* __restrict__ zb1,
    const float* __restrict__ W2, const float* __restrict__ a2,
    unsigned short* __restrict__ zb2,
    float* __restrict__ s_src2, float* __restrict__ s_dst2, int N)
{
    __shared__ float W2l[32 * 32];      // 4 KB
    __shared__ float2 wsbuf[8 * 128];   // 8 KB
    int tid = threadIdx.x;
    for (int i = tid; i < 1024; i += 256) W2l[i] = W2[i];
    __syncthreads();

    int g    = tid >> 5;
    int lane = tid & 31;
    int node = blockIdx.x * 8 + g;
    if (node >= N) return;
    float2* ws = &wsbuf[g * 128];

    AGG32_CORE(s_src1, s_dst1, zb1)

    // fused gemm2: z2[node][lane] = sum_k h1[k] * W2[k][lane]
    float acc2 = 0.f;
#pragma unroll
    for (int k = 0; k < 32; ++k)
        acc2 += __shfl(v, k, 32) * W2l[k * 32 + lane];

    zb2[(size_t)node * 32 + lane] = f2bf(acc2);
    float ps = acc2 * a2[lane];
    float pd = acc2 * a2[32 + lane];
#pragma unroll
    for (int off = 16; off > 0; off >>= 1) {
        ps += __shfl_xor(ps, off, 32);
        pd += __shfl_xor(pd, off, 32);
    }
    if (lane == 0) { s_src2[node] = ps; s_dst2[node] = pd; }
}

// ---- layer 2 agg, fused with gemm3 epilogue: emits zs={z3,z3*a0}, s_dst3 ----
__global__ __launch_bounds__(256) void agg32_l2_kernel(
    const int* __restrict__ offsets, const int* __restrict__ csr_src,
    const float* __restrict__ s_src2, const float* __restrict__ s_dst2,
    const unsigned short* __restrict__ zb2,
    const float* __restrict__ W3, const float* __restrict__ a3,
    float2* __restrict__ zs, float* __restrict__ s_dst3, int N)
{
    __shared__ float2 wsbuf[8 * 128];
    int tid  = threadIdx.x;
    int g    = tid >> 5;
    int lane = tid & 31;
    int node = blockIdx.x * 8 + g;
    if (node >= N) return;
    float2* ws = &wsbuf[g * 128];
    float w3 = W3[lane];

    AGG32_CORE(s_src2, s_dst2, zb2)

    // fused gemm3: z3 = sum_lane h2[lane] * W3[lane]
    float t = v * w3;
#pragma unroll
    for (int off = 16; off > 0; off >>= 1) t += __shfl_xor(t, off, 32);
    if (lane == 0) {
        zs[node] = make_float2(t, t * a3[0]);
        s_dst3[node] = t * a3[1];
    }
}

// ---- layer 3: fully edge-parallel, one 8B fp32 gather per edge, sigmoid ----
__global__ __launch_bounds__(256) void agg1_fused_kernel(
    const int* __restrict__ offsets, const int* __restrict__ csr_src,
    const float2* __restrict__ zs, const float* __restrict__ s_dst,
    float* __restrict__ out, int N)
{
    int node = blockIdx.x * 8 + (threadIdx.x >> 5);
    int lane = threadIdx.x & 31;
    if (node >= N) return;

    int beg = offsets[node], end = offsets[node + 1];
    int deg = end - beg;
    float sd = s_dst[node];

    if (deg <= 128) {
        float ev[4], zv[4];
        int nIter = (deg + 31) >> 5;
        float m = -3.0e38f;
#pragma unroll 4
        for (int it = 0; it < nIter; ++it) {
            int p = beg + it * 32 + lane;
            float e = -3.0e38f, zz = 0.f;
            if (p < end) {
                float2 v2 = zs[csr_src[p]];
                zz = v2.x;
                e = v2.y + sd;
                e = (e > 0.f) ? e : NEG_SLOPE * e;
            }
            ev[it] = e; zv[it] = zz;
            m = fmaxf(m, e);
        }
#pragma unroll
        for (int off = 16; off > 0; off >>= 1) m = fmaxf(m, __shfl_xor(m, off, 32));
        float l = 0.f, o = 0.f;
#pragma unroll 4
        for (int it = 0; it < nIter; ++it) {
            int p = beg + it * 32 + lane;
            float w = (p < end) ? __expf(ev[it] - m) : 0.f;
            l += w;
            o += w * zv[it];
        }
#pragma unroll
        for (int off = 16; off > 0; off >>= 1) {
            l += __shfl_xor(l, off, 32);
            o += __shfl_xor(o, off, 32);
        }
        if (lane == 0) {
            float v = o / fmaxf(l, 1e-9f);
            out[node] = 1.f / (1.f + __expf(-v));
        }
    } else {
        float m = -3.0e38f;
        for (int p = beg + lane; p < end; p += 32) {
            float e = zs[csr_src[p]].y + sd;
            e = (e > 0.f) ? e : NEG_SLOPE * e;
            m = fmaxf(m, e);
        }
#pragma unroll
        for (int off = 16; off > 0; off >>= 1) m = fmaxf(m, __shfl_xor(m, off, 32));
        float l = 0.f, o = 0.f;
        for (int p = beg + lane; p < end; p += 32) {
            float2 v2 = zs[csr_src[p]];
            float e = v2.y + sd;
            e = (e > 0.f) ? e : NEG_SLOPE * e;
            float w = __expf(e - m);
            l += w; o += w * v2.x;
        }
#pragma unroll
        for (int off = 16; off > 0; off >>= 1) {
            l += __shfl_xor(l, off, 32);
            o += __shfl_xor(o, off, 32);
        }
        if (lane == 0) {
            float v = o / fmaxf(l, 1e-9f);
            out[node] = 1.f / (1.f + __expf(-v));
        }
    }
}

// ============================================================================

extern "C" void kernel_launch(void* const* d_in, const int* in_sizes, int n_in,
                              void* d_out, int out_size, void* d_ws, size_t ws_size,
                              hipStream_t stream)
{
    const float* feature = (const float*)d_in[0];
    const int*   src     = (const int*)d_in[1];
    const int*   dst     = (const int*)d_in[2];
    const float* W1      = (const float*)d_in[3];
    const float* a1      = (const float*)d_in[4];
    const float* W2      = (const float*)d_in[5];
    const float* a2      = (const float*)d_in[6];
    const float* W3      = (const float*)d_in[7];
    const float* a3      = (const float*)d_in[8];
    float* out = (float*)d_out;

    const int N = in_sizes[0] / 128;
    const int E = in_sizes[1];

    const int TB = (E + TILE_E - 1) / TILE_E;
    const int NB = (N + 255) >> 8;
    const int M  = NB * TB;

    // ---- workspace layout ----
    char* p = (char*)d_ws;
    unsigned short* zb1 = (unsigned short*)p;  p += (size_t)N * 32 * sizeof(unsigned short);
    unsigned short* zb2 = (unsigned short*)p;  p += (size_t)N * 32 * sizeof(unsigned short);
    float* zs32    = (float*)p;  p += (size_t)N * 2 * sizeof(float);
    float* s_src1  = (float*)p;  p += (size_t)N * sizeof(float);
    float* s_dst1  = (float*)p;  p += (size_t)N * sizeof(float);
    float* s_src2  = (float*)p;  p += (size_t)N * sizeof(float);
    float* s_dst2  = (float*)p;  p += (size_t)N * sizeof(float);
    float* s_dst3  = (float*)p;  p += (size_t)N * sizeof(float);
    int*   offsets = (int*)p;    p += ((size_t)N + 1) * sizeof(int);
    int*   counts  = (int*)p;    p += ((size_t)M + 1) * sizeof(int);
    int*   cscan   = (int*)p;    p += ((size_t)M + 1) * sizeof(int);
    int*   blockSums = (int*)p;  p += 1024 * sizeof(int);
    int*   ebuf    = (int*)p;    p += (size_t)E * sizeof(int);
    int*   csr_src = (int*)p;    p += (size_t)E * sizeof(int);

    const int nodeBlocks8  = (N + 7) / 8;
    const int gemmBlocks64 = (N + 63) / 64;
    const int scanBlocksM  = (M + 255) / 256;

    // ---- build CSR: atomic-free two-level counting sort ----
    hipLaunchKernelGGL(csr_hist_kernel, dim3(TB), dim3(256), 0, stream,
                       dst, counts, E, TB, NB);
    hipLaunchKernelGGL(scan1_kernel, dim3(scanBlocksM), dim3(256), 0, stream,
                       counts, cscan, blockSums, M);
    hipLaunchKernelGGL(scan2_kernel, dim3(1), dim3(1024), 0, stream,
                       blockSums, scanBlocksM);
    hipLaunchKernelGGL(scan3_kernel, dim3(scanBlocksM), dim3(256), 0, stream,
                       counts, blockSums, cscan, M, E);
    hipLaunchKernelGGL(csr_scatter_kernel, dim3(TB), dim3(256), 0, stream,
                       src, dst, cscan, ebuf, E, TB, NB);
    hipLaunchKernelGGL(csr_bucket_kernel, dim3(NB), dim3(256), 0, stream,
                       ebuf, cscan, csr_src, offsets, N, E, TB);

    // ---- layer 1: gemm1 -> z1; agg(l1) fused with gemm2 -> z2 ----
    hipLaunchKernelGGL(gemm1_kernel, dim3(gemmBlocks64), dim3(128), 0, stream,
                       feature, W1, a1, zb1, s_src1, s_dst1, N);
    hipLaunchKernelGGL(agg32_l1_kernel, dim3(nodeBlocks8), dim3(256), 0, stream,
                       offsets, csr_src, s_src1, s_dst1, zb1, W2, a2,
                       zb2, s_src2, s_dst2, N);

    // ---- layer 2: agg(l2) fused with gemm3 -> zs, s_dst3 ----
    float2* zs = (float2*)zs32;
    hipLaunchKernelGGL(agg32_l2_kernel, dim3(nodeBlocks8), dim3(256), 0, stream,
                       offsets, csr_src, s_src2, s_dst2, zb2, W3, a3,
                       zs, s_dst3, N);

    // ---- layer 3: edge-parallel agg + sigmoid ----
    hipLaunchKernelGGL(agg1_fused_kernel, dim3(nodeBlocks8), dim3(256), 0, stream,
                       offsets, csr_src, zs, s_dst3, out, N);
}